// Round 1
// baseline (364.003 us; speedup 1.0000x reference)
//
#include <hip/hip_runtime.h>
#include <hip/hip_bf16.h>
#include <math.h>

#define N_NODES 50000
#define N_EDGES 500000
#define C_DIM 128
#define N_TILES 3125   // 50000/16 exact

#define CSR_BLOCKS 1954      // ceil(500000/256)
#define CONCAT_BLOCKS 3125   // 50000*16/256
#define PACK_BLOCKS 480      // (20*8*512 + 20*4*512)/256

typedef __attribute__((ext_vector_type(8))) short bf8;
typedef __attribute__((ext_vector_type(4))) float f32x4;

__device__ __forceinline__ float bflo(unsigned u) { return __uint_as_float(u << 16); }
__device__ __forceinline__ float bfhi(unsigned u) { return __uint_as_float(u & 0xffff0000u); }
__device__ __forceinline__ unsigned short f2bfu(float f) {
    __hip_bfloat16 h = __float2bfloat16(f);
    unsigned short u;
    __builtin_memcpy(&u, &h, 2);
    return u;
}
__device__ __forceinline__ unsigned packbf(float a, float b) {
    return ((unsigned)f2bfu(b) << 16) | f2bfu(a);
}

// ---------------- graph preprocessing ----------------

__global__ void count_deg(const int* __restrict__ row, const int* __restrict__ col,
                          int* __restrict__ dout, int* __restrict__ din, int e) {
    int i = blockIdx.x * blockDim.x + threadIdx.x;
    if (i >= e) return;
    atomicAdd(&dout[row[i]], 1);
    atomicAdd(&din[col[i]], 1);
}

__global__ void scan_block(const int* __restrict__ counts, int* __restrict__ excl,
                           int* __restrict__ blocksums, int n) {
    __shared__ int tmp[1024];
    int tid = threadIdx.x;
    int gid = blockIdx.x * 1024 + tid;
    int v = (gid < n) ? counts[gid] : 0;
    tmp[tid] = v;
    __syncthreads();
    for (int off = 1; off < 1024; off <<= 1) {
        int t = (tid >= off) ? tmp[tid - off] : 0;
        __syncthreads();
        tmp[tid] += t;
        __syncthreads();
    }
    int incl = tmp[tid];
    if (gid < n) excl[gid] = incl - v;
    if (tid == 1023) blocksums[blockIdx.x] = incl;
}

__global__ void scan_sums(int* __restrict__ blocksums, int nb) {
    __shared__ int tmp[64];
    int tid = threadIdx.x;
    int v = (tid < nb) ? blocksums[tid] : 0;
    tmp[tid] = v;
    __syncthreads();
    for (int off = 1; off < 64; off <<= 1) {
        int t = (tid >= off) ? tmp[tid - off] : 0;
        __syncthreads();
        tmp[tid] += t;
        __syncthreads();
    }
    if (tid < nb) blocksums[tid] = tmp[tid] - v;
}

__global__ void scan_add(int* __restrict__ rowptr, const int* __restrict__ blocksums,
                         int* __restrict__ cursor, const int* __restrict__ dout,
                         const int* __restrict__ din, float2* __restrict__ winv,
                         int n, int e_total) {
    int gid = blockIdx.x * blockDim.x + threadIdx.x;
    if (gid < n) {
        int v = rowptr[gid] + blocksums[gid >> 10];
        rowptr[gid] = v;
        cursor[gid] = v;
        winv[gid] = make_float2(1.0f / (float)dout[gid], 1.0f / (float)din[gid]);
    }
    if (gid == n) rowptr[n] = e_total;
}

// ---------------- weight helpers ----------------
__device__ __forceinline__ float wraw(const float* W, int d, int kk, int k, int j) {
    return W[((d * 3 + kk) * 128 + k) * 64 + j];
}

__device__ __forceinline__ float zr_val(const float* Wz, const float* Wr, int k, int nn) {
    const float* W = (nn < 64) ? Wz : Wr;
    int j = nn & 63;
    if (k < 128) return wraw(W, 0, 0, k, j) + wraw(W, 1, 0, k, j);
    int k2 = k - 128;
    int kk = (k2 >= 256) ? 2 : 1;
    int k3 = k2 & 255;
    int p = k3 >> 2, sub = k3 & 3;
    return wraw(W, sub >> 1, kk, 2 * p + (sub & 1), j);
}

__device__ __forceinline__ float h_val(const float* Wh, int k, int j) {
    if (k < 64) return wraw(Wh, 0, 0, k, j) + wraw(Wh, 1, 0, k, j);
    if (k < 320) {
        int k2 = k - 64;
        int kk = (k2 >= 128) ? 2 : 1;
        int k3 = k2 & 127;
        int p = k3 >> 2, sub = k3 & 3;
        return wraw(Wh, sub >> 1, kk, 2 * p + (sub & 1), j);
    }
    if (k < 384) return wraw(Wh, 0, 0, 64 + (k - 320), j) + wraw(Wh, 1, 0, 64 + (k - 320), j);
    int k2 = k - 384;
    int kk = (k2 >= 128) ? 2 : 1;
    int k3 = k2 & 127;
    int p = k3 >> 2, sub = k3 & 3;
    return wraw(Wh, sub >> 1, kk, 64 + 2 * p + (sub & 1), j);
}

// ---------------- fused prep: build_csr + concat_xh + pack_weights ----------
__global__ void fused_prep(const int* __restrict__ row, const int* __restrict__ col,
                           const float2* __restrict__ winv, int* __restrict__ cursor,
                           int* __restrict__ csr_src, float2* __restrict__ csr_w,
                           const float* __restrict__ X, const float* __restrict__ Hm,
                           unsigned short* __restrict__ XH, unsigned short* __restrict__ XHp,
                           const float* Wz, const float* Wr,
                           const float* Wh,
                           unsigned short* __restrict__ Wzrf, unsigned short* __restrict__ Whf,
                           int n, int e) {
    int b = blockIdx.x;
    if (b < CSR_BLOCKS) {
        int i = b * 256 + threadIdx.x;
        if (i >= e) return;
        int r = row[i], c = col[i];
        int pos = atomicAdd(&cursor[c], 1);
        csr_src[pos] = r;
        csr_w[pos] = winv[r];
    } else if (b < CSR_BLOCKS + CONCAT_BLOCKS) {
        int t = (b - CSR_BLOCKS) * 256 + threadIdx.x;   // < n*16 exactly
        int node = t >> 4, p = t & 15;
        const float* src = (p < 8) ? (X + (size_t)node * 64 + 8 * p)
                                   : (Hm + (size_t)node * 64 + 8 * (p - 8));
        float4 v0 = *(const float4*)src;
        float4 v1 = *(const float4*)(src + 4);
        uint4 o;
        o.x = packbf(v0.x, v0.y); o.y = packbf(v0.z, v0.w);
        o.z = packbf(v1.x, v1.y); o.w = packbf(v1.z, v1.w);
        *(uint4*)(XH + (size_t)node * 128 + 8 * p) = o;
        int tile = node >> 4, lr = node & 15, ck = p >> 2, q = p & 3;
        *(uint4*)(XHp + (((size_t)tile * 4 + ck) * 64 + q * 16 + lr) * 8) = o;
    } else {
        int i = (b - CSR_BLOCKS - CONCAT_BLOCKS) * 256 + threadIdx.x;
        if (i < 20 * 8 * 64 * 8) {
            int j = i & 7, lane = (i >> 3) & 63, nt = (i >> 9) & 7, ks = i >> 12;
            int k = ks * 32 + (lane >> 4) * 8 + j;
            int nn = nt * 16 + (lane & 15);
            Wzrf[i] = f2bfu(zr_val(Wz, Wr, k, nn));
        } else if (i < 20 * 8 * 64 * 8 + 20 * 4 * 64 * 8) {
            int i2 = i - 20 * 8 * 64 * 8;
            int j = i2 & 7, lane = (i2 >> 3) & 63, nt = (i2 >> 9) & 3, ks = i2 >> 11;
            int k = ks * 32 + (lane >> 4) * 8 + j;
            int nn = nt * 16 + (lane & 15);
            Whf[i2] = f2bfu(h_val(Wh, k, nn));
        }
    }
}

// ---------------- diffusion props ----------------
// P1 row-major [n][256] + packed P1p; P2 packed-only. Q1 row-major [n][128] +
// packed Q1p; Q2 packed-only. Packed: T[tile][ck][lane][8].

__global__ void prop1_128(const unsigned short* __restrict__ S,
                          const int* __restrict__ rowptr, const int* __restrict__ src,
                          const float2* __restrict__ w,
                          unsigned short* __restrict__ P1, unsigned short* __restrict__ P1p,
                          int n) {
    int tid = blockIdx.x * blockDim.x + threadIdx.x;
    int lane = tid & 63;
    int node = ((tid >> 6) << 1) + (lane >> 5);
    int p = lane & 31;
    if (node >= n) return;
    int beg = rowptr[node], end = rowptr[node + 1];
    float ao0 = 0.f, ao1 = 0.f, ao2 = 0.f, ao3 = 0.f;
    float ai0 = 0.f, ai1 = 0.f, ai2 = 0.f, ai3 = 0.f;
    int j = beg;
#define P1STEP(s_, w_) {                                                     \
        uint2 u = *(const uint2*)(S + (size_t)(s_) * 128 + 4 * p);           \
        float c0 = bflo(u.x), c1 = bfhi(u.x), c2 = bflo(u.y), c3 = bfhi(u.y);\
        ao0 = fmaf(w_.x, c0, ao0); ao1 = fmaf(w_.x, c1, ao1);                \
        ao2 = fmaf(w_.x, c2, ao2); ao3 = fmaf(w_.x, c3, ao3);                \
        ai0 = fmaf(w_.y, c0, ai0); ai1 = fmaf(w_.y, c1, ai1);                \
        ai2 = fmaf(w_.y, c2, ai2); ai3 = fmaf(w_.y, c3, ai3); }
    for (; j + 8 <= end; j += 8) {
        int s0 = src[j], s1 = src[j + 1], s2 = src[j + 2], s3 = src[j + 3];
        int s4 = src[j + 4], s5 = src[j + 5], s6 = src[j + 6], s7 = src[j + 7];
        float2 w0 = w[j], w1 = w[j + 1], w2 = w[j + 2], w3 = w[j + 3];
        float2 w4 = w[j + 4], w5 = w[j + 5], w6 = w[j + 6], w7 = w[j + 7];
        P1STEP(s0, w0); P1STEP(s1, w1); P1STEP(s2, w2); P1STEP(s3, w3);
        P1STEP(s4, w4); P1STEP(s5, w5); P1STEP(s6, w6); P1STEP(s7, w7);
    }
    for (; j + 4 <= end; j += 4) {
        int s0 = src[j], s1 = src[j + 1], s2 = src[j + 2], s3 = src[j + 3];
        float2 w0 = w[j], w1 = w[j + 1], w2 = w[j + 2], w3 = w[j + 3];
        P1STEP(s0, w0); P1STEP(s1, w1); P1STEP(s2, w2); P1STEP(s3, w3);
    }
    for (; j < end; ++j) {
        int s = src[j]; float2 wv = w[j];
        P1STEP(s, wv);
    }
#undef P1STEP
    uint4 o;
    o.x = packbf(ao0, ao1); o.y = packbf(ai0, ai1);
    o.z = packbf(ao2, ao3); o.w = packbf(ai2, ai3);
    *(uint4*)(P1 + (size_t)node * 256 + 8 * p) = o;
    int tile = node >> 4, lr = node & 15, ck = p >> 2, q = p & 3;
    *(uint4*)(P1p + (((size_t)tile * 8 + ck) * 64 + q * 16 + lr) * 8) = o;
}

__global__ void prop2_128(const unsigned short* __restrict__ P1,
                          const unsigned short* __restrict__ Xc,
                          const int* __restrict__ rowptr, const int* __restrict__ src,
                          const float2* __restrict__ w,
                          unsigned short* __restrict__ P2p, int n) {
    int tid = blockIdx.x * blockDim.x + threadIdx.x;
    int lane = tid & 63;
    int node = ((tid >> 6) << 1) + (lane >> 5);
    int p = lane & 31;
    if (node >= n) return;
    int beg = rowptr[node], end = rowptr[node + 1];
    float oa = 0.f, ob = 0.f, oc = 0.f, od = 0.f;
    float ia = 0.f, ib = 0.f, ic = 0.f, id = 0.f;
    int j = beg;
#define P2STEP(s_, w_) {                                                     \
        uint4 v = *(const uint4*)(P1 + (size_t)(s_) * 256 + 8 * p);          \
        oa = fmaf(w_.x, bflo(v.x), oa); ob = fmaf(w_.x, bfhi(v.x), ob);      \
        ia = fmaf(w_.y, bflo(v.y), ia); ib = fmaf(w_.y, bfhi(v.y), ib);      \
        oc = fmaf(w_.x, bflo(v.z), oc); od = fmaf(w_.x, bfhi(v.z), od);      \
        ic = fmaf(w_.y, bflo(v.w), ic); id = fmaf(w_.y, bfhi(v.w), id); }
    for (; j + 8 <= end; j += 8) {
        int s0 = src[j], s1 = src[j + 1], s2 = src[j + 2], s3 = src[j + 3];
        int s4 = src[j + 4], s5 = src[j + 5], s6 = src[j + 6], s7 = src[j + 7];
        float2 w0 = w[j], w1 = w[j + 1], w2 = w[j + 2], w3 = w[j + 3];
        float2 w4 = w[j + 4], w5 = w[j + 5], w6 = w[j + 6], w7 = w[j + 7];
        P2STEP(s0, w0); P2STEP(s1, w1); P2STEP(s2, w2); P2STEP(s3, w3);
        P2STEP(s4, w4); P2STEP(s5, w5); P2STEP(s6, w6); P2STEP(s7, w7);
    }
    for (; j + 4 <= end; j += 4) {
        int s0 = src[j], s1 = src[j + 1], s2 = src[j + 2], s3 = src[j + 3];
        float2 w0 = w[j], w1 = w[j + 1], w2 = w[j + 2], w3 = w[j + 3];
        P2STEP(s0, w0); P2STEP(s1, w1); P2STEP(s2, w2); P2STEP(s3, w3);
    }
    for (; j < end; ++j) {
        int s = src[j]; float2 wv = w[j];
        P2STEP(s, wv);
    }
#undef P2STEP
    uint2 ux = *(const uint2*)(Xc + (size_t)node * 128 + 4 * p);
    float xa = bflo(ux.x), xb = bfhi(ux.x), xc = bflo(ux.y), xd = bfhi(ux.y);
    uint4 o;
    o.x = packbf(2.f * oa - xa, 2.f * ob - xb);
    o.y = packbf(2.f * ia - xa, 2.f * ib - xb);
    o.z = packbf(2.f * oc - xc, 2.f * od - xd);
    o.w = packbf(2.f * ic - xc, 2.f * id - xd);
    int tile = node >> 4, lr = node & 15, ck = p >> 2, q = p & 3;
    *(uint4*)(P2p + (((size_t)tile * 8 + ck) * 64 + q * 16 + lr) * 8) = o;
}

__global__ void prop1_64(const unsigned short* __restrict__ HR,
                         const int* __restrict__ rowptr, const int* __restrict__ src,
                         const float2* __restrict__ w,
                         unsigned short* __restrict__ Q1, unsigned short* __restrict__ Q1p,
                         int n) {
    int tid = blockIdx.x * blockDim.x + threadIdx.x;
    int lane = tid & 63;
    int node = ((tid >> 6) << 2) + (lane >> 4);
    int p = lane & 15;
    if (node >= n) return;
    int beg = rowptr[node], end = rowptr[node + 1];
    float ao0 = 0.f, ao1 = 0.f, ao2 = 0.f, ao3 = 0.f;
    float ai0 = 0.f, ai1 = 0.f, ai2 = 0.f, ai3 = 0.f;
    int j = beg;
#define Q1STEP(s_, w_) {                                                     \
        uint2 u = *(const uint2*)(HR + (size_t)(s_) * 64 + 4 * p);           \
        float c0 = bflo(u.x), c1 = bfhi(u.x), c2 = bflo(u.y), c3 = bfhi(u.y);\
        ao0 = fmaf(w_.x, c0, ao0); ao1 = fmaf(w_.x, c1, ao1);                \
        ao2 = fmaf(w_.x, c2, ao2); ao3 = fmaf(w_.x, c3, ao3);                \
        ai0 = fmaf(w_.y, c0, ai0); ai1 = fmaf(w_.y, c1, ai1);                \
        ai2 = fmaf(w_.y, c2, ai2); ai3 = fmaf(w_.y, c3, ai3); }
    for (; j + 8 <= end; j += 8) {
        int s0 = src[j], s1 = src[j + 1], s2 = src[j + 2], s3 = src[j + 3];
        int s4 = src[j + 4], s5 = src[j + 5], s6 = src[j + 6], s7 = src[j + 7];
        float2 w0 = w[j], w1 = w[j + 1], w2 = w[j + 2], w3 = w[j + 3];
        float2 w4 = w[j + 4], w5 = w[j + 5], w6 = w[j + 6], w7 = w[j + 7];
        Q1STEP(s0, w0); Q1STEP(s1, w1); Q1STEP(s2, w2); Q1STEP(s3, w3);
        Q1STEP(s4, w4); Q1STEP(s5, w5); Q1STEP(s6, w6); Q1STEP(s7, w7);
    }
    for (; j + 4 <= end; j += 4) {
        int s0 = src[j], s1 = src[j + 1], s2 = src[j + 2], s3 = src[j + 3];
        float2 w0 = w[j], w1 = w[j + 1], w2 = w[j + 2], w3 = w[j + 3];
        Q1STEP(s0, w0); Q1STEP(s1, w1); Q1STEP(s2, w2); Q1STEP(s3, w3);
    }
    for (; j < end; ++j) {
        int s = src[j]; float2 wv = w[j];
        Q1STEP(s, wv);
    }
#undef Q1STEP
    uint4 o;
    o.x = packbf(ao0, ao1); o.y = packbf(ai0, ai1);
    o.z = packbf(ao2, ao3); o.w = packbf(ai2, ai3);
    *(uint4*)(Q1 + (size_t)node * 128 + 8 * p) = o;
    int tile = node >> 4, lr = node & 15, ck = p >> 2, q = p & 3;
    *(uint4*)(Q1p + (((size_t)tile * 4 + ck) * 64 + q * 16 + lr) * 8) = o;
}

__global__ void prop2_64(const unsigned short* __restrict__ Q1,
                         const unsigned short* __restrict__ HR,
                         const int* __restrict__ rowptr, const int* __restrict__ src,
                         const float2* __restrict__ w,
                         unsigned short* __restrict__ Q2p, int n) {
    int tid = blockIdx.x * blockDim.x + threadIdx.x;
    int lane = tid & 63;
    int node = ((tid >> 6) << 2) + (lane >> 4);
    int p = lane & 15;
    if (node >= n) return;
    int beg = rowptr[node], end = rowptr[node + 1];
    float oa = 0.f, ob = 0.f, oc = 0.f, od = 0.f;
    float ia = 0.f, ib = 0.f, ic = 0.f, id = 0.f;
    int j = beg;
#define Q2STEP(s_, w_) {                                                     \
        uint4 v = *(const uint4*)(Q1 + (size_t)(s_) * 128 + 8 * p);          \
        oa = fmaf(w_.x, bflo(v.x), oa); ob = fmaf(w_.x, bfhi(v.x), ob);      \
        ia = fmaf(w_.y, bflo(v.y), ia); ib = fmaf(w_.y, bfhi(v.y), ib);      \
        oc = fmaf(w_.x, bflo(v.z), oc); od = fmaf(w_.x, bfhi(v.z), od);      \
        ic = fmaf(w_.y, bflo(v.w), ic); id = fmaf(w_.y, bfhi(v.w), id); }
    for (; j + 8 <= end; j += 8) {
        int s0 = src[j], s1 = src[j + 1], s2 = src[j + 2], s3 = src[j + 3];
        int s4 = src[j + 4], s5 = src[j + 5], s6 = src[j + 6], s7 = src[j + 7];
        float2 w0 = w[j], w1 = w[j + 1], w2 = w[j + 2], w3 = w[j + 3];
        float2 w4 = w[j + 4], w5 = w[j + 5], w6 = w[j + 6], w7 = w[j + 7];
        Q2STEP(s0, w0); Q2STEP(s1, w1); Q2STEP(s2, w2); Q2STEP(s3, w3);
        Q2STEP(s4, w4); Q2STEP(s5, w5); Q2STEP(s6, w6); Q2STEP(s7, w7);
    }
    for (; j + 4 <= end; j += 4) {
        int s0 = src[j], s1 = src[j + 1], s2 = src[j + 2], s3 = src[j + 3];
        float2 w0 = w[j], w1 = w[j + 1], w2 = w[j + 2], w3 = w[j + 3];
        Q2STEP(s0, w0); Q2STEP(s1, w1); Q2STEP(s2, w2); Q2STEP(s3, w3);
    }
    for (; j < end; ++j) {
        int s = src[j]; float2 wv = w[j];
        Q2STEP(s, wv);
    }
#undef Q2STEP
    uint2 ux = *(const uint2*)(HR + (size_t)node * 64 + 4 * p);
    float xa = bflo(ux.x), xb = bfhi(ux.x), xc = bflo(ux.y), xd = bfhi(ux.y);
    uint4 o;
    o.x = packbf(2.f * oa - xa, 2.f * ob - xb);
    o.y = packbf(2.f * ia - xa, 2.f * ib - xb);
    o.z = packbf(2.f * oc - xc, 2.f * od - xd);
    o.w = packbf(2.f * ic - xc, 2.f * id - xd);
    int tile = node >> 4, lr = node & 15, ck = p >> 2, q = p & 3;
    *(uint4*)(Q2p + (((size_t)tile * 4 + ck) * 64 + q * 16 + lr) * 8) = o;
}

// ---------------- MFMA GEMMs: fragment-packed A and B, no LDS, no barriers --
// All frag loads are coalesced 1KB wave loads: lane i reads 16B at base+16i.
// mfma_f32_16x16x32_bf16 C/D: col=lane&15, row=(lane>>4)*4+reg.

// ZR: block 64 rows x 128 cols; 4 waves each 64 rows x 32 cols (ngrp = wid).
__global__ __launch_bounds__(256) void gemm_zr_mfma(
    const unsigned short* __restrict__ XHp, const unsigned short* __restrict__ P1p,
    const unsigned short* __restrict__ P2p,
    const unsigned short* __restrict__ Wf, const float* bz,
    const float* br, const float* __restrict__ H,
    float* __restrict__ Zf, unsigned short* __restrict__ HR, int n) {
    int tid = threadIdx.x;
    int lane = tid & 63;
    int ngrp = tid >> 6;
    int rowbase = blockIdx.x * 64;
    int lr = lane & 15, quad = lane >> 4;

    int tiles[4];
#pragma unroll
    for (int mt = 0; mt < 4; ++mt) {
        int t = (rowbase >> 4) + mt;
        tiles[mt] = (t > N_TILES - 1) ? N_TILES - 1 : t;
    }

    f32x4 zero = {0.f, 0.f, 0.f, 0.f};
    f32x4 acc[4][2];
#pragma unroll
    for (int a = 0; a < 4; ++a)
#pragma unroll
        for (int b = 0; b < 2; ++b) acc[a][b] = zero;

#pragma unroll
    for (int ks = 0; ks < 20; ++ks) {
        const unsigned short* T = (ks < 4) ? XHp : (ks < 12) ? P1p : P2p;
        int ck = (ks < 4) ? ks : (ks < 12) ? ks - 4 : ks - 12;
        int nck = (ks < 4) ? 4 : 8;
        bf8 b0 = *(const bf8*)(Wf + (((size_t)ks * 8 + ngrp * 2 + 0) * 64 + lane) * 8);
        bf8 b1 = *(const bf8*)(Wf + (((size_t)ks * 8 + ngrp * 2 + 1) * 64 + lane) * 8);
#pragma unroll
        for (int mt = 0; mt < 4; ++mt) {
            bf8 a = *(const bf8*)(T + (((size_t)tiles[mt] * nck + ck) * 64 + lane) * 8);
            acc[mt][0] = __builtin_amdgcn_mfma_f32_16x16x32_bf16(a, b0, acc[mt][0], 0, 0, 0);
            acc[mt][1] = __builtin_amdgcn_mfma_f32_16x16x32_bf16(a, b1, acc[mt][1], 0, 0, 0);
        }
    }
#pragma unroll
    for (int mt = 0; mt < 4; ++mt)
#pragma unroll
        for (int reg = 0; reg < 4; ++reg) {
            int r = rowbase + mt * 16 + quad * 4 + reg;
            if (r >= n) continue;
#pragma unroll
            for (int nt = 0; nt < 2; ++nt) {
                int cidx = ngrp * 32 + nt * 16 + lr;
                float bias = (cidx < 64) ? bz[cidx] : br[cidx - 64];
                float v = acc[mt][nt][reg] + bias;
                float s = 1.f / (1.f + expf(-v));
                if (cidx < 64) {
                    Zf[(size_t)r * 64 + cidx] = s;
                } else {
                    int c2 = cidx - 64;
                    HR[(size_t)r * 64 + c2] = f2bfu(H[(size_t)r * 64 + c2] * s);
                }
            }
        }
}

// H~: block 128 rows x 64 cols; 4 waves = (mh = wid&1 row-half, ngrp = wid>>1),
// each 64 rows x 32 cols. ks: 0-1 XHp, 2-5 P1p, 6-9 P2p(X-half), 10-11 HR
// (row-major strided, only 2/20), 12-15 Q1p, 16-19 Q2p.
__global__ __launch_bounds__(256) void gemm_h_mfma(
    const unsigned short* __restrict__ XHp, const unsigned short* __restrict__ P1p,
    const unsigned short* __restrict__ P2p, const unsigned short* __restrict__ HR,
    const unsigned short* __restrict__ Q1p, const unsigned short* __restrict__ Q2p,
    const unsigned short* __restrict__ Wf, const float* bh,
    const float* __restrict__ Zf, const float* __restrict__ H,
    float* __restrict__ out, int n) {
    int tid = threadIdx.x;
    int lane = tid & 63;
    int wid = tid >> 6;
    int mh = wid & 1, ngrp = wid >> 1;
    int rowbase = blockIdx.x * 128 + mh * 64;
    int lr = lane & 15, quad = lane >> 4;

    int tiles[4];
    const unsigned short* hrp[4];
#pragma unroll
    for (int mt = 0; mt < 4; ++mt) {
        int t = (rowbase >> 4) + mt;
        tiles[mt] = (t > N_TILES - 1) ? N_TILES - 1 : t;
        int r = rowbase + mt * 16 + lr;
        if (r >= n) r = n - 1;
        hrp[mt] = HR + (size_t)r * 64 + quad * 8;
    }

    f32x4 zero = {0.f, 0.f, 0.f, 0.f};
    f32x4 acc[4][2];
#pragma unroll
    for (int a = 0; a < 4; ++a)
#pragma unroll
        for (int b = 0; b < 2; ++b) acc[a][b] = zero;

#pragma unroll
    for (int ks = 0; ks < 20; ++ks) {
        bf8 b0 = *(const bf8*)(Wf + (((size_t)ks * 4 + ngrp * 2 + 0) * 64 + lane) * 8);
        bf8 b1 = *(const bf8*)(Wf + (((size_t)ks * 4 + ngrp * 2 + 1) * 64 + lane) * 8);
#pragma unroll
        for (int mt = 0; mt < 4; ++mt) {
            bf8 a;
            if (ks == 10 || ks == 11) {
                a = *(const bf8*)(hrp[mt] + (ks - 10) * 32);
            } else {
                const unsigned short* T = (ks < 2) ? XHp : (ks < 6) ? P1p :
                                          (ks < 10) ? P2p : (ks < 16) ? Q1p : Q2p;
                int ck = (ks < 2) ? ks : (ks < 6) ? ks - 2 : (ks < 10) ? ks - 6 :
                         (ks < 16) ? ks - 12 : ks - 16;
                int nck = (ks < 2) ? 4 : (ks < 10) ? 8 : 4;
                a = *(const bf8*)(T + (((size_t)tiles[mt] * nck + ck) * 64 + lane) * 8);
            }
            acc[mt][0] = __builtin_amdgcn_mfma_f32_16x16x32_bf16(a, b0, acc[mt][0], 0, 0, 0);
            acc[mt][1] = __builtin_amdgcn_mfma_f32_16x16x32_bf16(a, b1, acc[mt][1], 0, 0, 0);
        }
    }
#pragma unroll
    for (int mt = 0; mt < 4; ++mt)
#pragma unroll
        for (int reg = 0; reg < 4; ++reg) {
            int r = rowbase + mt * 16 + quad * 4 + reg;
            if (r >= n) continue;
#pragma unroll
            for (int nt = 0; nt < 2; ++nt) {
                int cidx = ngrp * 32 + nt * 16 + lr;
                float ht = tanhf(acc[mt][nt][reg] + bh[cidx]);
                float z = Zf[(size_t)r * 64 + cidx];
                float h_old = H[(size_t)r * 64 + cidx];
                out[(size_t)r * 64 + cidx] = z * h_old + (1.f - z) * ht;
            }
        }
}

// ---------------- launch ----------------

static inline size_t rup(size_t x) { return (x + 63) & ~(size_t)63; }

extern "C" void kernel_launch(void* const* d_in, const int* in_sizes, int n_in,
                              void* d_out, int out_size, void* d_ws, size_t ws_size,
                              hipStream_t stream) {
    const float* X  = (const float*)d_in[0];
    const int*   EI = (const int*)d_in[1];
    const float* H  = (const float*)d_in[2];
    const float* Wz = (const float*)d_in[3];
    const float* bz = (const float*)d_in[4];
    const float* Wr = (const float*)d_in[5];
    const float* br = (const float*)d_in[6];
    const float* Wh = (const float*)d_in[7];
    const float* bh = (const float*)d_in[8];
    float* out = (float*)d_out;

    const int* row = EI;
    const int* col = EI + N_EDGES;

    char* ws = (char*)d_ws;
    size_t off = 0;
    auto carve = [&](size_t bytes) { void* p = ws + off; off += rup(bytes); return p; };

    int*   deg_out   = (int*)carve(N_NODES * 4);
    int*   deg_in    = (int*)carve(N_NODES * 4);
    int*   rowptr    = (int*)carve((N_NODES + 1) * 4);
    int*   cursor    = (int*)carve(N_NODES * 4);
    int*   blocksums = (int*)carve(64 * 4);
    float2* winv     = (float2*)carve(N_NODES * 8);
    int*   csr_src   = (int*)carve(N_EDGES * 4);
    float2* csr_w    = (float2*)carve(N_EDGES * 8);
    unsigned short* XH  = (unsigned short*)carve((size_t)N_NODES * 128 * 2);  // dead after prop2_128
    unsigned short* P1  = (unsigned short*)carve((size_t)N_NODES * 256 * 2);  // dead after prop2_128
    unsigned short* XHp = (unsigned short*)carve((size_t)N_TILES * 4 * 512 * 2);
    unsigned short* P1p = (unsigned short*)carve((size_t)N_TILES * 8 * 512 * 2);
    unsigned short* P2p = (unsigned short*)carve((size_t)N_TILES * 8 * 512 * 2);
    unsigned short* HR  = (unsigned short*)carve((size_t)N_NODES * 64 * 2);
    float* Zf           = (float*)carve((size_t)N_NODES * 64 * 4);
    unsigned short* Wzrf = (unsigned short*)carve(20 * 8 * 64 * 8 * 2);
    unsigned short* Whf  = (unsigned short*)carve(20 * 4 * 64 * 8 * 2);

    // Aliases (regions dead by the time these are written):
    unsigned short* Q1  = XH;                                  // [n][128] row-major
    unsigned short* Q1p = P1;                                  // fragment-packed, 12.8 MB
    unsigned short* Q2p = P1 + (size_t)N_TILES * 4 * 512;      // fragment-packed, 12.8 MB

    hipMemsetAsync(deg_out, 0, rup(N_NODES * 4) + rup(N_NODES * 4), stream);
    count_deg<<<(N_EDGES + 255) / 256, 256, 0, stream>>>(row, col, deg_out, deg_in, N_EDGES);

    int nblk = (N_NODES + 1023) / 1024;
    scan_block<<<nblk, 1024, 0, stream>>>(deg_in, rowptr, blocksums, N_NODES);
    scan_sums<<<1, 64, 0, stream>>>(blocksums, nblk);
    scan_add<<<(N_NODES + 1 + 255) / 256, 256, 0, stream>>>(rowptr, blocksums, cursor,
                                                            deg_out, deg_in, winv, N_NODES, N_EDGES);

    // fused: build_csr + concat_xh + pack_weights
    fused_prep<<<CSR_BLOCKS + CONCAT_BLOCKS + PACK_BLOCKS, 256, 0, stream>>>(
        row, col, winv, cursor, csr_src, csr_w,
        X, H, XH, XHp, Wz, Wr, Wh, Wzrf, Whf, N_NODES, N_EDGES);

    // props on XH: 2 nodes/wave
    int blocks_p128 = (((N_NODES + 1) / 2) * 64 + 255) / 256;
    prop1_128<<<blocks_p128, 256, 0, stream>>>(XH, rowptr, csr_src, csr_w, P1, P1p, N_NODES);
    prop2_128<<<blocks_p128, 256, 0, stream>>>(P1, XH, rowptr, csr_src, csr_w, P2p, N_NODES);

    // Z|R GEMM -> Zf, HR   (XH, P1 row-major now dead)
    int zr_blocks = (N_NODES + 63) / 64;
    gemm_zr_mfma<<<zr_blocks, 256, 0, stream>>>(XHp, P1p, P2p, Wzrf, bz, br, H, Zf, HR, N_NODES);

    // props on HR: 4 nodes/wave
    int blocks_p64 = (((N_NODES + 3) / 4) * 64 + 255) / 256;
    prop1_64<<<blocks_p64, 256, 0, stream>>>(HR, rowptr, csr_src, csr_w, Q1, Q1p, N_NODES);
    prop2_64<<<blocks_p64, 256, 0, stream>>>(Q1, HR, rowptr, csr_src, csr_w, Q2p, N_NODES);

    // H~ GEMM + GRU mix -> out
    int h_blocks = (N_NODES + 127) / 128;
    gemm_h_mfma<<<h_blocks, 256, 0, stream>>>(XHp, P1p, P2p, HR, Q1p, Q2p,
                                              Whf, bh, Zf, H, out, N_NODES);
}

// Round 2
// 343.005 us; speedup vs baseline: 1.0612x; 1.0612x over previous
//
#include <hip/hip_runtime.h>
#include <hip/hip_bf16.h>
#include <math.h>

#define N_NODES 50000
#define N_EDGES 500000
#define C_DIM 128
#define N_TILES 3125   // 50000/16 exact

#define CSR_BLOCKS 1954      // ceil(500000/256)
#define CONCAT_BLOCKS 3125   // 50000*16/256
#define PACK_BLOCKS 480      // (20*8*512 + 20*4*512)/256

typedef __attribute__((ext_vector_type(8))) short bf8;
typedef __attribute__((ext_vector_type(4))) float f32x4;
typedef __attribute__((ext_vector_type(2))) float f32x2;

__device__ __forceinline__ float bflo(unsigned u) { return __uint_as_float(u << 16); }
__device__ __forceinline__ float bfhi(unsigned u) { return __uint_as_float(u & 0xffff0000u); }
__device__ __forceinline__ unsigned short f2bfu(float f) {
    __hip_bfloat16 h = __float2bfloat16(f);
    unsigned short u;
    __builtin_memcpy(&u, &h, 2);
    return u;
}
__device__ __forceinline__ unsigned packbf(float a, float b) {
    return ((unsigned)f2bfu(b) << 16) | f2bfu(a);
}

// ---------------- graph preprocessing ----------------

__global__ void count_deg(const int* __restrict__ row, const int* __restrict__ col,
                          int* __restrict__ dout, int* __restrict__ din, int e) {
    int i = blockIdx.x * blockDim.x + threadIdx.x;
    if (i >= e) return;
    atomicAdd(&dout[row[i]], 1);
    atomicAdd(&din[col[i]], 1);
}

__global__ void scan_block(const int* __restrict__ counts, int* __restrict__ excl,
                           int* __restrict__ blocksums, int n) {
    __shared__ int tmp[1024];
    int tid = threadIdx.x;
    int gid = blockIdx.x * 1024 + tid;
    int v = (gid < n) ? counts[gid] : 0;
    tmp[tid] = v;
    __syncthreads();
    for (int off = 1; off < 1024; off <<= 1) {
        int t = (tid >= off) ? tmp[tid - off] : 0;
        __syncthreads();
        tmp[tid] += t;
        __syncthreads();
    }
    int incl = tmp[tid];
    if (gid < n) excl[gid] = incl - v;
    if (tid == 1023) blocksums[blockIdx.x] = incl;
}

__global__ void scan_sums(int* __restrict__ blocksums, int nb) {
    __shared__ int tmp[64];
    int tid = threadIdx.x;
    int v = (tid < nb) ? blocksums[tid] : 0;
    tmp[tid] = v;
    __syncthreads();
    for (int off = 1; off < 64; off <<= 1) {
        int t = (tid >= off) ? tmp[tid - off] : 0;
        __syncthreads();
        tmp[tid] += t;
        __syncthreads();
    }
    if (tid < nb) blocksums[tid] = tmp[tid] - v;
}

__global__ void scan_add(int* __restrict__ rowptr, const int* __restrict__ blocksums,
                         int* __restrict__ cursor, const int* __restrict__ dout,
                         const int* __restrict__ din, float2* __restrict__ winv,
                         int n, int e_total) {
    int gid = blockIdx.x * blockDim.x + threadIdx.x;
    if (gid < n) {
        int v = rowptr[gid] + blocksums[gid >> 10];
        rowptr[gid] = v;
        cursor[gid] = v;
        winv[gid] = make_float2(1.0f / (float)dout[gid], 1.0f / (float)din[gid]);
    }
    if (gid == n) rowptr[n] = e_total;
}

// ---------------- weight helpers ----------------
__device__ __forceinline__ float wraw(const float* W, int d, int kk, int k, int j) {
    return W[((d * 3 + kk) * 128 + k) * 64 + j];
}

__device__ __forceinline__ float zr_val(const float* Wz, const float* Wr, int k, int nn) {
    const float* W = (nn < 64) ? Wz : Wr;
    int j = nn & 63;
    if (k < 128) return wraw(W, 0, 0, k, j) + wraw(W, 1, 0, k, j);
    int k2 = k - 128;
    int kk = (k2 >= 256) ? 2 : 1;
    int k3 = k2 & 255;
    int p = k3 >> 2, sub = k3 & 3;
    return wraw(W, sub >> 1, kk, 2 * p + (sub & 1), j);
}

__device__ __forceinline__ float h_val(const float* Wh, int k, int j) {
    if (k < 64) return wraw(Wh, 0, 0, k, j) + wraw(Wh, 1, 0, k, j);
    if (k < 320) {
        int k2 = k - 64;
        int kk = (k2 >= 128) ? 2 : 1;
        int k3 = k2 & 127;
        int p = k3 >> 2, sub = k3 & 3;
        return wraw(Wh, sub >> 1, kk, 2 * p + (sub & 1), j);
    }
    if (k < 384) return wraw(Wh, 0, 0, 64 + (k - 320), j) + wraw(Wh, 1, 0, 64 + (k - 320), j);
    int k2 = k - 384;
    int kk = (k2 >= 128) ? 2 : 1;
    int k3 = k2 & 127;
    int p = k3 >> 2, sub = k3 & 3;
    return wraw(Wh, sub >> 1, kk, 64 + 2 * p + (sub & 1), j);
}

// ---------------- fused prep: build_csr + concat_xh + pack_weights ----------
__global__ void fused_prep(const int* __restrict__ row, const int* __restrict__ col,
                           const float2* __restrict__ winv, int* __restrict__ cursor,
                           int* __restrict__ csr_src, float2* __restrict__ csr_w,
                           const float* __restrict__ X, const float* __restrict__ Hm,
                           unsigned short* __restrict__ XH, unsigned short* __restrict__ XHp,
                           const float* Wz, const float* Wr,
                           const float* Wh,
                           unsigned short* __restrict__ Wzrf, unsigned short* __restrict__ Whf,
                           int n, int e) {
    int b = blockIdx.x;
    if (b < CSR_BLOCKS) {
        int i = b * 256 + threadIdx.x;
        if (i >= e) return;
        int r = row[i], c = col[i];
        int pos = atomicAdd(&cursor[c], 1);
        csr_src[pos] = r;
        csr_w[pos] = winv[r];
    } else if (b < CSR_BLOCKS + CONCAT_BLOCKS) {
        int t = (b - CSR_BLOCKS) * 256 + threadIdx.x;   // < n*16 exactly
        int node = t >> 4, p = t & 15;
        const float* src = (p < 8) ? (X + (size_t)node * 64 + 8 * p)
                                   : (Hm + (size_t)node * 64 + 8 * (p - 8));
        float4 v0 = *(const float4*)src;
        float4 v1 = *(const float4*)(src + 4);
        uint4 o;
        o.x = packbf(v0.x, v0.y); o.y = packbf(v0.z, v0.w);
        o.z = packbf(v1.x, v1.y); o.w = packbf(v1.z, v1.w);
        *(uint4*)(XH + (size_t)node * 128 + 8 * p) = o;
        int tile = node >> 4, lr = node & 15, ck = p >> 2, q = p & 3;
        *(uint4*)(XHp + (((size_t)tile * 4 + ck) * 64 + q * 16 + lr) * 8) = o;
    } else {
        int i = (b - CSR_BLOCKS - CONCAT_BLOCKS) * 256 + threadIdx.x;
        if (i < 20 * 8 * 64 * 8) {
            int j = i & 7, lane = (i >> 3) & 63, nt = (i >> 9) & 7, ks = i >> 12;
            int k = ks * 32 + (lane >> 4) * 8 + j;
            int nn = nt * 16 + (lane & 15);
            Wzrf[i] = f2bfu(zr_val(Wz, Wr, k, nn));
        } else if (i < 20 * 8 * 64 * 8 + 20 * 4 * 64 * 8) {
            int i2 = i - 20 * 8 * 64 * 8;
            int j = i2 & 7, lane = (i2 >> 3) & 63, nt = (i2 >> 9) & 3, ks = i2 >> 11;
            int k = ks * 32 + (lane >> 4) * 8 + j;
            int nn = nt * 16 + (lane & 15);
            Whf[i2] = f2bfu(h_val(Wh, k, nn));
        }
    }
}

// ---------------- diffusion props ----------------
// P1: fp8 row-major [n][256] (gather src for prop2_128) + bf16 packed P1p;
// P2 packed-only. Q1: fp8 row-major [n][128] + bf16 packed Q1p; Q2 packed-only.
// Packed: T[tile][ck][lane][8] bf16. fp8 = OCP e4m3 via HW cvt.

__global__ void prop1_128(const unsigned short* __restrict__ S,
                          const int* __restrict__ rowptr, const int* __restrict__ src,
                          const float2* __restrict__ w,
                          unsigned char* __restrict__ P18, unsigned short* __restrict__ P1p,
                          int n) {
    int tid = blockIdx.x * blockDim.x + threadIdx.x;
    int lane = tid & 63;
    int node = ((tid >> 6) << 1) + (lane >> 5);
    int p = lane & 31;
    if (node >= n) return;
    int beg = rowptr[node], end = rowptr[node + 1];
    float ao0 = 0.f, ao1 = 0.f, ao2 = 0.f, ao3 = 0.f;
    float ai0 = 0.f, ai1 = 0.f, ai2 = 0.f, ai3 = 0.f;
    int j = beg;
#define P1STEP(s_, w_) {                                                     \
        uint2 u = *(const uint2*)(S + (size_t)(s_) * 128 + 4 * p);           \
        float c0 = bflo(u.x), c1 = bfhi(u.x), c2 = bflo(u.y), c3 = bfhi(u.y);\
        ao0 = fmaf(w_.x, c0, ao0); ao1 = fmaf(w_.x, c1, ao1);                \
        ao2 = fmaf(w_.x, c2, ao2); ao3 = fmaf(w_.x, c3, ao3);                \
        ai0 = fmaf(w_.y, c0, ai0); ai1 = fmaf(w_.y, c1, ai1);                \
        ai2 = fmaf(w_.y, c2, ai2); ai3 = fmaf(w_.y, c3, ai3); }
    for (; j + 8 <= end; j += 8) {
        int s0 = src[j], s1 = src[j + 1], s2 = src[j + 2], s3 = src[j + 3];
        int s4 = src[j + 4], s5 = src[j + 5], s6 = src[j + 6], s7 = src[j + 7];
        float2 w0 = w[j], w1 = w[j + 1], w2 = w[j + 2], w3 = w[j + 3];
        float2 w4 = w[j + 4], w5 = w[j + 5], w6 = w[j + 6], w7 = w[j + 7];
        P1STEP(s0, w0); P1STEP(s1, w1); P1STEP(s2, w2); P1STEP(s3, w3);
        P1STEP(s4, w4); P1STEP(s5, w5); P1STEP(s6, w6); P1STEP(s7, w7);
    }
    for (; j + 4 <= end; j += 4) {
        int s0 = src[j], s1 = src[j + 1], s2 = src[j + 2], s3 = src[j + 3];
        float2 w0 = w[j], w1 = w[j + 1], w2 = w[j + 2], w3 = w[j + 3];
        P1STEP(s0, w0); P1STEP(s1, w1); P1STEP(s2, w2); P1STEP(s3, w3);
    }
    for (; j < end; ++j) {
        int s = src[j]; float2 wv = w[j];
        P1STEP(s, wv);
    }
#undef P1STEP
    // fp8 row-major for the next-hop gather (bytes: ao0,ao1,ai0,ai1,ao2,ao3,ai2,ai3)
    unsigned wa = (unsigned)__builtin_amdgcn_cvt_pk_fp8_f32(ao0, ao1, 0, false);
    wa = (unsigned)__builtin_amdgcn_cvt_pk_fp8_f32(ai0, ai1, wa, true);
    unsigned wb = (unsigned)__builtin_amdgcn_cvt_pk_fp8_f32(ao2, ao3, 0, false);
    wb = (unsigned)__builtin_amdgcn_cvt_pk_fp8_f32(ai2, ai3, wb, true);
    uint2 o8; o8.x = wa; o8.y = wb;
    *(uint2*)(P18 + (size_t)node * 256 + 8 * p) = o8;
    // bf16 fragments for the GEMM (unchanged precision)
    uint4 o;
    o.x = packbf(ao0, ao1); o.y = packbf(ai0, ai1);
    o.z = packbf(ao2, ao3); o.w = packbf(ai2, ai3);
    int tile = node >> 4, lr = node & 15, ck = p >> 2, q = p & 3;
    *(uint4*)(P1p + (((size_t)tile * 8 + ck) * 64 + q * 16 + lr) * 8) = o;
}

__global__ void prop2_128(const unsigned char* __restrict__ P18,
                          const unsigned short* __restrict__ Xc,
                          const int* __restrict__ rowptr, const int* __restrict__ src,
                          const float2* __restrict__ w,
                          unsigned short* __restrict__ P2p, int n) {
    int tid = blockIdx.x * blockDim.x + threadIdx.x;
    int lane = tid & 63;
    int node = ((tid >> 6) << 1) + (lane >> 5);
    int p = lane & 31;
    if (node >= n) return;
    int beg = rowptr[node], end = rowptr[node + 1];
    float oa = 0.f, ob = 0.f, oc = 0.f, od = 0.f;
    float ia = 0.f, ib = 0.f, ic = 0.f, id = 0.f;
    int j = beg;
#define P2STEP(s_, w_) {                                                     \
        uint2 v = *(const uint2*)(P18 + (size_t)(s_) * 256 + 8 * p);         \
        f32x2 f0 = __builtin_amdgcn_cvt_pk_f32_fp8(v.x, false);              \
        f32x2 f1 = __builtin_amdgcn_cvt_pk_f32_fp8(v.x, true);               \
        f32x2 f2 = __builtin_amdgcn_cvt_pk_f32_fp8(v.y, false);              \
        f32x2 f3 = __builtin_amdgcn_cvt_pk_f32_fp8(v.y, true);               \
        oa = fmaf(w_.x, f0[0], oa); ob = fmaf(w_.x, f0[1], ob);              \
        ia = fmaf(w_.y, f1[0], ia); ib = fmaf(w_.y, f1[1], ib);              \
        oc = fmaf(w_.x, f2[0], oc); od = fmaf(w_.x, f2[1], od);              \
        ic = fmaf(w_.y, f3[0], ic); id = fmaf(w_.y, f3[1], id); }
    for (; j + 8 <= end; j += 8) {
        int s0 = src[j], s1 = src[j + 1], s2 = src[j + 2], s3 = src[j + 3];
        int s4 = src[j + 4], s5 = src[j + 5], s6 = src[j + 6], s7 = src[j + 7];
        float2 w0 = w[j], w1 = w[j + 1], w2 = w[j + 2], w3 = w[j + 3];
        float2 w4 = w[j + 4], w5 = w[j + 5], w6 = w[j + 6], w7 = w[j + 7];
        P2STEP(s0, w0); P2STEP(s1, w1); P2STEP(s2, w2); P2STEP(s3, w3);
        P2STEP(s4, w4); P2STEP(s5, w5); P2STEP(s6, w6); P2STEP(s7, w7);
    }
    for (; j + 4 <= end; j += 4) {
        int s0 = src[j], s1 = src[j + 1], s2 = src[j + 2], s3 = src[j + 3];
        float2 w0 = w[j], w1 = w[j + 1], w2 = w[j + 2], w3 = w[j + 3];
        P2STEP(s0, w0); P2STEP(s1, w1); P2STEP(s2, w2); P2STEP(s3, w3);
    }
    for (; j < end; ++j) {
        int s = src[j]; float2 wv = w[j];
        P2STEP(s, wv);
    }
#undef P2STEP
    uint2 ux = *(const uint2*)(Xc + (size_t)node * 128 + 4 * p);
    float xa = bflo(ux.x), xb = bfhi(ux.x), xc = bflo(ux.y), xd = bfhi(ux.y);
    uint4 o;
    o.x = packbf(2.f * oa - xa, 2.f * ob - xb);
    o.y = packbf(2.f * ia - xa, 2.f * ib - xb);
    o.z = packbf(2.f * oc - xc, 2.f * od - xd);
    o.w = packbf(2.f * ic - xc, 2.f * id - xd);
    int tile = node >> 4, lr = node & 15, ck = p >> 2, q = p & 3;
    *(uint4*)(P2p + (((size_t)tile * 8 + ck) * 64 + q * 16 + lr) * 8) = o;
}

__global__ void prop1_64(const unsigned short* __restrict__ HR,
                         const int* __restrict__ rowptr, const int* __restrict__ src,
                         const float2* __restrict__ w,
                         unsigned char* __restrict__ Q18, unsigned short* __restrict__ Q1p,
                         int n) {
    int tid = blockIdx.x * blockDim.x + threadIdx.x;
    int lane = tid & 63;
    int node = ((tid >> 6) << 2) + (lane >> 4);
    int p = lane & 15;
    if (node >= n) return;
    int beg = rowptr[node], end = rowptr[node + 1];
    float ao0 = 0.f, ao1 = 0.f, ao2 = 0.f, ao3 = 0.f;
    float ai0 = 0.f, ai1 = 0.f, ai2 = 0.f, ai3 = 0.f;
    int j = beg;
#define Q1STEP(s_, w_) {                                                     \
        uint2 u = *(const uint2*)(HR + (size_t)(s_) * 64 + 4 * p);           \
        float c0 = bflo(u.x), c1 = bfhi(u.x), c2 = bflo(u.y), c3 = bfhi(u.y);\
        ao0 = fmaf(w_.x, c0, ao0); ao1 = fmaf(w_.x, c1, ao1);                \
        ao2 = fmaf(w_.x, c2, ao2); ao3 = fmaf(w_.x, c3, ao3);                \
        ai0 = fmaf(w_.y, c0, ai0); ai1 = fmaf(w_.y, c1, ai1);                \
        ai2 = fmaf(w_.y, c2, ai2); ai3 = fmaf(w_.y, c3, ai3); }
    for (; j + 8 <= end; j += 8) {
        int s0 = src[j], s1 = src[j + 1], s2 = src[j + 2], s3 = src[j + 3];
        int s4 = src[j + 4], s5 = src[j + 5], s6 = src[j + 6], s7 = src[j + 7];
        float2 w0 = w[j], w1 = w[j + 1], w2 = w[j + 2], w3 = w[j + 3];
        float2 w4 = w[j + 4], w5 = w[j + 5], w6 = w[j + 6], w7 = w[j + 7];
        Q1STEP(s0, w0); Q1STEP(s1, w1); Q1STEP(s2, w2); Q1STEP(s3, w3);
        Q1STEP(s4, w4); Q1STEP(s5, w5); Q1STEP(s6, w6); Q1STEP(s7, w7);
    }
    for (; j + 4 <= end; j += 4) {
        int s0 = src[j], s1 = src[j + 1], s2 = src[j + 2], s3 = src[j + 3];
        float2 w0 = w[j], w1 = w[j + 1], w2 = w[j + 2], w3 = w[j + 3];
        Q1STEP(s0, w0); Q1STEP(s1, w1); Q1STEP(s2, w2); Q1STEP(s3, w3);
    }
    for (; j < end; ++j) {
        int s = src[j]; float2 wv = w[j];
        Q1STEP(s, wv);
    }
#undef Q1STEP
    unsigned wa = (unsigned)__builtin_amdgcn_cvt_pk_fp8_f32(ao0, ao1, 0, false);
    wa = (unsigned)__builtin_amdgcn_cvt_pk_fp8_f32(ai0, ai1, wa, true);
    unsigned wb = (unsigned)__builtin_amdgcn_cvt_pk_fp8_f32(ao2, ao3, 0, false);
    wb = (unsigned)__builtin_amdgcn_cvt_pk_fp8_f32(ai2, ai3, wb, true);
    uint2 o8; o8.x = wa; o8.y = wb;
    *(uint2*)(Q18 + (size_t)node * 128 + 8 * p) = o8;
    uint4 o;
    o.x = packbf(ao0, ao1); o.y = packbf(ai0, ai1);
    o.z = packbf(ao2, ao3); o.w = packbf(ai2, ai3);
    int tile = node >> 4, lr = node & 15, ck = p >> 2, q = p & 3;
    *(uint4*)(Q1p + (((size_t)tile * 4 + ck) * 64 + q * 16 + lr) * 8) = o;
}

__global__ void prop2_64(const unsigned char* __restrict__ Q18,
                         const unsigned short* __restrict__ HR,
                         const int* __restrict__ rowptr, const int* __restrict__ src,
                         const float2* __restrict__ w,
                         unsigned short* __restrict__ Q2p, int n) {
    int tid = blockIdx.x * blockDim.x + threadIdx.x;
    int lane = tid & 63;
    int node = ((tid >> 6) << 2) + (lane >> 4);
    int p = lane & 15;
    if (node >= n) return;
    int beg = rowptr[node], end = rowptr[node + 1];
    float oa = 0.f, ob = 0.f, oc = 0.f, od = 0.f;
    float ia = 0.f, ib = 0.f, ic = 0.f, id = 0.f;
    int j = beg;
#define Q2STEP(s_, w_) {                                                     \
        uint2 v = *(const uint2*)(Q18 + (size_t)(s_) * 128 + 8 * p);         \
        f32x2 f0 = __builtin_amdgcn_cvt_pk_f32_fp8(v.x, false);              \
        f32x2 f1 = __builtin_amdgcn_cvt_pk_f32_fp8(v.x, true);               \
        f32x2 f2 = __builtin_amdgcn_cvt_pk_f32_fp8(v.y, false);              \
        f32x2 f3 = __builtin_amdgcn_cvt_pk_f32_fp8(v.y, true);               \
        oa = fmaf(w_.x, f0[0], oa); ob = fmaf(w_.x, f0[1], ob);              \
        ia = fmaf(w_.y, f1[0], ia); ib = fmaf(w_.y, f1[1], ib);              \
        oc = fmaf(w_.x, f2[0], oc); od = fmaf(w_.x, f2[1], od);              \
        ic = fmaf(w_.y, f3[0], ic); id = fmaf(w_.y, f3[1], id); }
    for (; j + 8 <= end; j += 8) {
        int s0 = src[j], s1 = src[j + 1], s2 = src[j + 2], s3 = src[j + 3];
        int s4 = src[j + 4], s5 = src[j + 5], s6 = src[j + 6], s7 = src[j + 7];
        float2 w0 = w[j], w1 = w[j + 1], w2 = w[j + 2], w3 = w[j + 3];
        float2 w4 = w[j + 4], w5 = w[j + 5], w6 = w[j + 6], w7 = w[j + 7];
        Q2STEP(s0, w0); Q2STEP(s1, w1); Q2STEP(s2, w2); Q2STEP(s3, w3);
        Q2STEP(s4, w4); Q2STEP(s5, w5); Q2STEP(s6, w6); Q2STEP(s7, w7);
    }
    for (; j + 4 <= end; j += 4) {
        int s0 = src[j], s1 = src[j + 1], s2 = src[j + 2], s3 = src[j + 3];
        float2 w0 = w[j], w1 = w[j + 1], w2 = w[j + 2], w3 = w[j + 3];
        Q2STEP(s0, w0); Q2STEP(s1, w1); Q2STEP(s2, w2); Q2STEP(s3, w3);
    }
    for (; j < end; ++j) {
        int s = src[j]; float2 wv = w[j];
        Q2STEP(s, wv);
    }
#undef Q2STEP
    uint2 ux = *(const uint2*)(HR + (size_t)node * 64 + 4 * p);
    float xa = bflo(ux.x), xb = bfhi(ux.x), xc = bflo(ux.y), xd = bfhi(ux.y);
    uint4 o;
    o.x = packbf(2.f * oa - xa, 2.f * ob - xb);
    o.y = packbf(2.f * ia - xa, 2.f * ib - xb);
    o.z = packbf(2.f * oc - xc, 2.f * od - xd);
    o.w = packbf(2.f * ic - xc, 2.f * id - xd);
    int tile = node >> 4, lr = node & 15, ck = p >> 2, q = p & 3;
    *(uint4*)(Q2p + (((size_t)tile * 4 + ck) * 64 + q * 16 + lr) * 8) = o;
}

// ---------------- MFMA GEMMs: fragment-packed A and B, no LDS, no barriers --
// All frag loads are coalesced 1KB wave loads: lane i reads 16B at base+16i.
// mfma_f32_16x16x32_bf16 C/D: col=lane&15, row=(lane>>4)*4+reg.

// ZR: block 64 rows x 128 cols; 4 waves each 64 rows x 32 cols (ngrp = wid).
__global__ __launch_bounds__(256) void gemm_zr_mfma(
    const unsigned short* __restrict__ XHp, const unsigned short* __restrict__ P1p,
    const unsigned short* __restrict__ P2p,
    const unsigned short* __restrict__ Wf, const float* bz,
    const float* br, const float* __restrict__ H,
    float* __restrict__ Zf, unsigned short* __restrict__ HR, int n) {
    int tid = threadIdx.x;
    int lane = tid & 63;
    int ngrp = tid >> 6;
    int rowbase = blockIdx.x * 64;
    int lr = lane & 15, quad = lane >> 4;

    int tiles[4];
#pragma unroll
    for (int mt = 0; mt < 4; ++mt) {
        int t = (rowbase >> 4) + mt;
        tiles[mt] = (t > N_TILES - 1) ? N_TILES - 1 : t;
    }

    f32x4 zero = {0.f, 0.f, 0.f, 0.f};
    f32x4 acc[4][2];
#pragma unroll
    for (int a = 0; a < 4; ++a)
#pragma unroll
        for (int b = 0; b < 2; ++b) acc[a][b] = zero;

#pragma unroll
    for (int ks = 0; ks < 20; ++ks) {
        const unsigned short* T = (ks < 4) ? XHp : (ks < 12) ? P1p : P2p;
        int ck = (ks < 4) ? ks : (ks < 12) ? ks - 4 : ks - 12;
        int nck = (ks < 4) ? 4 : 8;
        bf8 b0 = *(const bf8*)(Wf + (((size_t)ks * 8 + ngrp * 2 + 0) * 64 + lane) * 8);
        bf8 b1 = *(const bf8*)(Wf + (((size_t)ks * 8 + ngrp * 2 + 1) * 64 + lane) * 8);
#pragma unroll
        for (int mt = 0; mt < 4; ++mt) {
            bf8 a = *(const bf8*)(T + (((size_t)tiles[mt] * nck + ck) * 64 + lane) * 8);
            acc[mt][0] = __builtin_amdgcn_mfma_f32_16x16x32_bf16(a, b0, acc[mt][0], 0, 0, 0);
            acc[mt][1] = __builtin_amdgcn_mfma_f32_16x16x32_bf16(a, b1, acc[mt][1], 0, 0, 0);
        }
    }
#pragma unroll
    for (int mt = 0; mt < 4; ++mt)
#pragma unroll
        for (int reg = 0; reg < 4; ++reg) {
            int r = rowbase + mt * 16 + quad * 4 + reg;
            if (r >= n) continue;
#pragma unroll
            for (int nt = 0; nt < 2; ++nt) {
                int cidx = ngrp * 32 + nt * 16 + lr;
                float bias = (cidx < 64) ? bz[cidx] : br[cidx - 64];
                float v = acc[mt][nt][reg] + bias;
                float s = 1.f / (1.f + expf(-v));
                if (cidx < 64) {
                    Zf[(size_t)r * 64 + cidx] = s;
                } else {
                    int c2 = cidx - 64;
                    HR[(size_t)r * 64 + c2] = f2bfu(H[(size_t)r * 64 + c2] * s);
                }
            }
        }
}

// H~: block 128 rows x 64 cols; 4 waves = (mh = wid&1 row-half, ngrp = wid>>1),
// each 64 rows x 32 cols. ks: 0-1 XHp, 2-5 P1p, 6-9 P2p(X-half), 10-11 HR
// (row-major strided, only 2/20), 12-15 Q1p, 16-19 Q2p.
__global__ __launch_bounds__(256) void gemm_h_mfma(
    const unsigned short* __restrict__ XHp, const unsigned short* __restrict__ P1p,
    const unsigned short* __restrict__ P2p, const unsigned short* __restrict__ HR,
    const unsigned short* __restrict__ Q1p, const unsigned short* __restrict__ Q2p,
    const unsigned short* __restrict__ Wf, const float* bh,
    const float* __restrict__ Zf, const float* __restrict__ H,
    float* __restrict__ out, int n) {
    int tid = threadIdx.x;
    int lane = tid & 63;
    int wid = tid >> 6;
    int mh = wid & 1, ngrp = wid >> 1;
    int rowbase = blockIdx.x * 128 + mh * 64;
    int lr = lane & 15, quad = lane >> 4;

    int tiles[4];
    const unsigned short* hrp[4];
#pragma unroll
    for (int mt = 0; mt < 4; ++mt) {
        int t = (rowbase >> 4) + mt;
        tiles[mt] = (t > N_TILES - 1) ? N_TILES - 1 : t;
        int r = rowbase + mt * 16 + lr;
        if (r >= n) r = n - 1;
        hrp[mt] = HR + (size_t)r * 64 + quad * 8;
    }

    f32x4 zero = {0.f, 0.f, 0.f, 0.f};
    f32x4 acc[4][2];
#pragma unroll
    for (int a = 0; a < 4; ++a)
#pragma unroll
        for (int b = 0; b < 2; ++b) acc[a][b] = zero;

#pragma unroll
    for (int ks = 0; ks < 20; ++ks) {
        bf8 b0 = *(const bf8*)(Wf + (((size_t)ks * 4 + ngrp * 2 + 0) * 64 + lane) * 8);
        bf8 b1 = *(const bf8*)(Wf + (((size_t)ks * 4 + ngrp * 2 + 1) * 64 + lane) * 8);
#pragma unroll
        for (int mt = 0; mt < 4; ++mt) {
            bf8 a;
            if (ks == 10 || ks == 11) {
                a = *(const bf8*)(hrp[mt] + (ks - 10) * 32);
            } else {
                const unsigned short* T = (ks < 2) ? XHp : (ks < 6) ? P1p :
                                          (ks < 10) ? P2p : (ks < 16) ? Q1p : Q2p;
                int ck = (ks < 2) ? ks : (ks < 6) ? ks - 2 : (ks < 10) ? ks - 6 :
                         (ks < 16) ? ks - 12 : ks - 16;
                int nck = (ks < 2) ? 4 : (ks < 10) ? 8 : 4;
                a = *(const bf8*)(T + (((size_t)tiles[mt] * nck + ck) * 64 + lane) * 8);
            }
            acc[mt][0] = __builtin_amdgcn_mfma_f32_16x16x32_bf16(a, b0, acc[mt][0], 0, 0, 0);
            acc[mt][1] = __builtin_amdgcn_mfma_f32_16x16x32_bf16(a, b1, acc[mt][1], 0, 0, 0);
        }
    }
#pragma unroll
    for (int mt = 0; mt < 4; ++mt)
#pragma unroll
        for (int reg = 0; reg < 4; ++reg) {
            int r = rowbase + mt * 16 + quad * 4 + reg;
            if (r >= n) continue;
#pragma unroll
            for (int nt = 0; nt < 2; ++nt) {
                int cidx = ngrp * 32 + nt * 16 + lr;
                float ht = tanhf(acc[mt][nt][reg] + bh[cidx]);
                float z = Zf[(size_t)r * 64 + cidx];
                float h_old = H[(size_t)r * 64 + cidx];
                out[(size_t)r * 64 + cidx] = z * h_old + (1.f - z) * ht;
            }
        }
}

// ---------------- launch ----------------

static inline size_t rup(size_t x) { return (x + 63) & ~(size_t)63; }

extern "C" void kernel_launch(void* const* d_in, const int* in_sizes, int n_in,
                              void* d_out, int out_size, void* d_ws, size_t ws_size,
                              hipStream_t stream) {
    const float* X  = (const float*)d_in[0];
    const int*   EI = (const int*)d_in[1];
    const float* H  = (const float*)d_in[2];
    const float* Wz = (const float*)d_in[3];
    const float* bz = (const float*)d_in[4];
    const float* Wr = (const float*)d_in[5];
    const float* br = (const float*)d_in[6];
    const float* Wh = (const float*)d_in[7];
    const float* bh = (const float*)d_in[8];
    float* out = (float*)d_out;

    const int* row = EI;
    const int* col = EI + N_EDGES;

    char* ws = (char*)d_ws;
    size_t off = 0;
    auto carve = [&](size_t bytes) { void* p = ws + off; off += rup(bytes); return p; };

    int*   deg_out   = (int*)carve(N_NODES * 4);
    int*   deg_in    = (int*)carve(N_NODES * 4);
    int*   rowptr    = (int*)carve((N_NODES + 1) * 4);
    int*   cursor    = (int*)carve(N_NODES * 4);
    int*   blocksums = (int*)carve(64 * 4);
    float2* winv     = (float2*)carve(N_NODES * 8);
    int*   csr_src   = (int*)carve(N_EDGES * 4);
    float2* csr_w    = (float2*)carve(N_EDGES * 8);
    unsigned short* XH  = (unsigned short*)carve((size_t)N_NODES * 128 * 2);  // dead after prop2_128
    unsigned char*  Pscr = (unsigned char*)carve((size_t)N_NODES * 256 + (size_t)N_TILES * 4 * 512 * 2);
    unsigned short* XHp = (unsigned short*)carve((size_t)N_TILES * 4 * 512 * 2);
    unsigned short* P1p = (unsigned short*)carve((size_t)N_TILES * 8 * 512 * 2);
    unsigned short* P2p = (unsigned short*)carve((size_t)N_TILES * 8 * 512 * 2);
    unsigned short* HR  = (unsigned short*)carve((size_t)N_NODES * 64 * 2);
    float* Zf           = (float*)carve((size_t)N_NODES * 64 * 4);
    unsigned short* Wzrf = (unsigned short*)carve(20 * 8 * 64 * 8 * 2);
    unsigned short* Whf  = (unsigned short*)carve(20 * 4 * 64 * 8 * 2);

    // P18 fp8 [n][256] lives in Pscr; dead after prop2_128, then Q1p/Q2p overlay it.
    unsigned char*  P18 = Pscr;                                // 12.8 MB fp8
    unsigned char*  Q18 = (unsigned char*)XH;                  // 6.4 MB fp8 (XH dead after prop2_128)
    unsigned short* Q1p = (unsigned short*)Pscr;               // 12.8 MB bf16 fragments
    unsigned short* Q2p = (unsigned short*)(Pscr + (size_t)N_NODES * 256);  // 12.8 MB

    hipMemsetAsync(deg_out, 0, rup(N_NODES * 4) + rup(N_NODES * 4), stream);
    count_deg<<<(N_EDGES + 255) / 256, 256, 0, stream>>>(row, col, deg_out, deg_in, N_EDGES);

    int nblk = (N_NODES + 1023) / 1024;
    scan_block<<<nblk, 1024, 0, stream>>>(deg_in, rowptr, blocksums, N_NODES);
    scan_sums<<<1, 64, 0, stream>>>(blocksums, nblk);
    scan_add<<<(N_NODES + 1 + 255) / 256, 256, 0, stream>>>(rowptr, blocksums, cursor,
                                                            deg_out, deg_in, winv, N_NODES, N_EDGES);

    // fused: build_csr + concat_xh + pack_weights
    fused_prep<<<CSR_BLOCKS + CONCAT_BLOCKS + PACK_BLOCKS, 256, 0, stream>>>(
        row, col, winv, cursor, csr_src, csr_w,
        X, H, XH, XHp, Wz, Wr, Wh, Wzrf, Whf, N_NODES, N_EDGES);

    // props on XH: 2 nodes/wave
    int blocks_p128 = (((N_NODES + 1) / 2) * 64 + 255) / 256;
    prop1_128<<<blocks_p128, 256, 0, stream>>>(XH, rowptr, csr_src, csr_w, P18, P1p, N_NODES);
    prop2_128<<<blocks_p128, 256, 0, stream>>>(P18, XH, rowptr, csr_src, csr_w, P2p, N_NODES);

    // Z|R GEMM -> Zf, HR   (XH, P18 now dead)
    int zr_blocks = (N_NODES + 63) / 64;
    gemm_zr_mfma<<<zr_blocks, 256, 0, stream>>>(XHp, P1p, P2p, Wzrf, bz, br, H, Zf, HR, N_NODES);

    // props on HR: 4 nodes/wave
    int blocks_p64 = (((N_NODES + 3) / 4) * 64 + 255) / 256;
    prop1_64<<<blocks_p64, 256, 0, stream>>>(HR, rowptr, csr_src, csr_w, Q18, Q1p, N_NODES);
    prop2_64<<<blocks_p64, 256, 0, stream>>>(Q18, HR, rowptr, csr_src, csr_w, Q2p, N_NODES);

    // H~ GEMM + GRU mix -> out
    int h_blocks = (N_NODES + 127) / 128;
    gemm_h_mfma<<<h_blocks, 256, 0, stream>>>(XHp, P1p, P2p, HR, Q1p, Q2p,
                                              Whf, bh, Zf, H, out, N_NODES);
}

// Round 3
// 328.869 us; speedup vs baseline: 1.1068x; 1.0430x over previous
//
#include <hip/hip_runtime.h>
#include <hip/hip_bf16.h>
#include <math.h>

#define N_NODES 50000
#define N_EDGES 500000
#define C_DIM 128
#define N_TILES 3125   // 50000/16 exact

#define CSR_BLOCKS 1954      // ceil(500000/256)
#define CONCAT_BLOCKS 3125   // 50000*16/256
#define PACK_BLOCKS 480      // (20*8*512 + 20*4*512)/256

typedef __attribute__((ext_vector_type(8))) short bf8;
typedef __attribute__((ext_vector_type(4))) float f32x4;
typedef __attribute__((ext_vector_type(2))) float f32x2;

__device__ __forceinline__ float bflo(unsigned u) { return __uint_as_float(u << 16); }
__device__ __forceinline__ float bfhi(unsigned u) { return __uint_as_float(u & 0xffff0000u); }
__device__ __forceinline__ unsigned short f2bfu(float f) {
    __hip_bfloat16 h = __float2bfloat16(f);
    unsigned short u;
    __builtin_memcpy(&u, &h, 2);
    return u;
}
__device__ __forceinline__ unsigned packbf(float a, float b) {
    return ((unsigned)f2bfu(b) << 16) | f2bfu(a);
}

// ---------------- graph preprocessing ----------------

__global__ void count_deg(const int* __restrict__ row, const int* __restrict__ col,
                          int* __restrict__ dout, int* __restrict__ din, int e) {
    int i = blockIdx.x * blockDim.x + threadIdx.x;
    if (i >= e) return;
    atomicAdd(&dout[row[i]], 1);
    atomicAdd(&din[col[i]], 1);
}

__global__ void scan_block(const int* __restrict__ counts, int* __restrict__ excl,
                           int* __restrict__ blocksums, int n) {
    __shared__ int tmp[1024];
    int tid = threadIdx.x;
    int gid = blockIdx.x * 1024 + tid;
    int v = (gid < n) ? counts[gid] : 0;
    tmp[tid] = v;
    __syncthreads();
    for (int off = 1; off < 1024; off <<= 1) {
        int t = (tid >= off) ? tmp[tid - off] : 0;
        __syncthreads();
        tmp[tid] += t;
        __syncthreads();
    }
    int incl = tmp[tid];
    if (gid < n) excl[gid] = incl - v;
    if (tid == 1023) blocksums[blockIdx.x] = incl;
}

__global__ void scan_sums(int* __restrict__ blocksums, int nb) {
    __shared__ int tmp[64];
    int tid = threadIdx.x;
    int v = (tid < nb) ? blocksums[tid] : 0;
    tmp[tid] = v;
    __syncthreads();
    for (int off = 1; off < 64; off <<= 1) {
        int t = (tid >= off) ? tmp[tid - off] : 0;
        __syncthreads();
        tmp[tid] += t;
        __syncthreads();
    }
    if (tid < nb) blocksums[tid] = tmp[tid] - v;
}

__global__ void scan_add(int* __restrict__ rowptr, const int* __restrict__ blocksums,
                         int* __restrict__ cursor, const int* __restrict__ dout,
                         const int* __restrict__ din, float2* __restrict__ winv,
                         int n, int e_total) {
    int gid = blockIdx.x * blockDim.x + threadIdx.x;
    if (gid < n) {
        int v = rowptr[gid] + blocksums[gid >> 10];
        rowptr[gid] = v;
        cursor[gid] = v;
        winv[gid] = make_float2(1.0f / (float)dout[gid], 1.0f / (float)din[gid]);
    }
    if (gid == n) rowptr[n] = e_total;
}

// ---------------- weight helpers ----------------
__device__ __forceinline__ float wraw(const float* W, int d, int kk, int k, int j) {
    return W[((d * 3 + kk) * 128 + k) * 64 + j];
}

__device__ __forceinline__ float zr_val(const float* Wz, const float* Wr, int k, int nn) {
    const float* W = (nn < 64) ? Wz : Wr;
    int j = nn & 63;
    if (k < 128) return wraw(W, 0, 0, k, j) + wraw(W, 1, 0, k, j);
    int k2 = k - 128;
    int kk = (k2 >= 256) ? 2 : 1;
    int k3 = k2 & 255;
    int p = k3 >> 2, sub = k3 & 3;
    return wraw(W, sub >> 1, kk, 2 * p + (sub & 1), j);
}

__device__ __forceinline__ float h_val(const float* Wh, int k, int j) {
    if (k < 64) return wraw(Wh, 0, 0, k, j) + wraw(Wh, 1, 0, k, j);
    if (k < 320) {
        int k2 = k - 64;
        int kk = (k2 >= 128) ? 2 : 1;
        int k3 = k2 & 127;
        int p = k3 >> 2, sub = k3 & 3;
        return wraw(Wh, sub >> 1, kk, 2 * p + (sub & 1), j);
    }
    if (k < 384) return wraw(Wh, 0, 0, 64 + (k - 320), j) + wraw(Wh, 1, 0, 64 + (k - 320), j);
    int k2 = k - 384;
    int kk = (k2 >= 128) ? 2 : 1;
    int k3 = k2 & 127;
    int p = k3 >> 2, sub = k3 & 3;
    return wraw(Wh, sub >> 1, kk, 64 + 2 * p + (sub & 1), j);
}

// ---------------- fused prep: build_csr + concat_xh + pack_weights ----------
// CSR carries ONLY src ids (4B scatter per edge). Edge weights are gathered
// as winv[src] inside the props (winv = 400KB, L2-resident).
__global__ void fused_prep(const int* __restrict__ row, const int* __restrict__ col,
                           int* __restrict__ cursor,
                           int* __restrict__ csr_src,
                           const float* __restrict__ X, const float* __restrict__ Hm,
                           unsigned short* __restrict__ XH, unsigned short* __restrict__ XHp,
                           const float* Wz, const float* Wr,
                           const float* Wh,
                           unsigned short* __restrict__ Wzrf, unsigned short* __restrict__ Whf,
                           int n, int e) {
    int b = blockIdx.x;
    if (b < CSR_BLOCKS) {
        int i = b * 256 + threadIdx.x;
        if (i >= e) return;
        int r = row[i], c = col[i];
        int pos = atomicAdd(&cursor[c], 1);
        csr_src[pos] = r;
    } else if (b < CSR_BLOCKS + CONCAT_BLOCKS) {
        int t = (b - CSR_BLOCKS) * 256 + threadIdx.x;   // < n*16 exactly
        int node = t >> 4, p = t & 15;
        const float* src = (p < 8) ? (X + (size_t)node * 64 + 8 * p)
                                   : (Hm + (size_t)node * 64 + 8 * (p - 8));
        float4 v0 = *(const float4*)src;
        float4 v1 = *(const float4*)(src + 4);
        uint4 o;
        o.x = packbf(v0.x, v0.y); o.y = packbf(v0.z, v0.w);
        o.z = packbf(v1.x, v1.y); o.w = packbf(v1.z, v1.w);
        *(uint4*)(XH + (size_t)node * 128 + 8 * p) = o;
        int tile = node >> 4, lr = node & 15, ck = p >> 2, q = p & 3;
        *(uint4*)(XHp + (((size_t)tile * 4 + ck) * 64 + q * 16 + lr) * 8) = o;
    } else {
        int i = (b - CSR_BLOCKS - CONCAT_BLOCKS) * 256 + threadIdx.x;
        if (i < 20 * 8 * 64 * 8) {
            int j = i & 7, lane = (i >> 3) & 63, nt = (i >> 9) & 7, ks = i >> 12;
            int k = ks * 32 + (lane >> 4) * 8 + j;
            int nn = nt * 16 + (lane & 15);
            Wzrf[i] = f2bfu(zr_val(Wz, Wr, k, nn));
        } else if (i < 20 * 8 * 64 * 8 + 20 * 4 * 64 * 8) {
            int i2 = i - 20 * 8 * 64 * 8;
            int j = i2 & 7, lane = (i2 >> 3) & 63, nt = (i2 >> 9) & 3, ks = i2 >> 11;
            int k = ks * 32 + (lane >> 4) * 8 + j;
            int nn = nt * 16 + (lane & 15);
            Whf[i2] = f2bfu(h_val(Wh, k, nn));
        }
    }
}

// ---------------- diffusion props ----------------
// P1: fp8 row-major [n][256] (gather src for prop2_128) + bf16 packed P1p;
// P2 packed-only. Q1: fp8 row-major [n][128] + bf16 packed Q1p; Q2 packed-only.
// Packed: T[tile][ck][lane][8] bf16. fp8 = OCP e4m3 via HW cvt.
// Edge weight = winv[src] gathered on the fly (L2-resident).

__global__ void prop1_128(const unsigned short* __restrict__ S,
                          const int* __restrict__ rowptr, const int* __restrict__ src,
                          const float2* __restrict__ winv,
                          unsigned char* __restrict__ P18, unsigned short* __restrict__ P1p,
                          int n) {
    int tid = blockIdx.x * blockDim.x + threadIdx.x;
    int lane = tid & 63;
    int node = ((tid >> 6) << 1) + (lane >> 5);
    int p = lane & 31;
    if (node >= n) return;
    int beg = rowptr[node], end = rowptr[node + 1];
    float ao0 = 0.f, ao1 = 0.f, ao2 = 0.f, ao3 = 0.f;
    float ai0 = 0.f, ai1 = 0.f, ai2 = 0.f, ai3 = 0.f;
    int j = beg;
#define P1STEP(s_, w_) {                                                     \
        uint2 u = *(const uint2*)(S + (size_t)(s_) * 128 + 4 * p);           \
        float c0 = bflo(u.x), c1 = bfhi(u.x), c2 = bflo(u.y), c3 = bfhi(u.y);\
        ao0 = fmaf(w_.x, c0, ao0); ao1 = fmaf(w_.x, c1, ao1);                \
        ao2 = fmaf(w_.x, c2, ao2); ao3 = fmaf(w_.x, c3, ao3);                \
        ai0 = fmaf(w_.y, c0, ai0); ai1 = fmaf(w_.y, c1, ai1);                \
        ai2 = fmaf(w_.y, c2, ai2); ai3 = fmaf(w_.y, c3, ai3); }
    for (; j + 8 <= end; j += 8) {
        int s0 = src[j], s1 = src[j + 1], s2 = src[j + 2], s3 = src[j + 3];
        int s4 = src[j + 4], s5 = src[j + 5], s6 = src[j + 6], s7 = src[j + 7];
        float2 w0 = winv[s0], w1 = winv[s1], w2 = winv[s2], w3 = winv[s3];
        float2 w4 = winv[s4], w5 = winv[s5], w6 = winv[s6], w7 = winv[s7];
        P1STEP(s0, w0); P1STEP(s1, w1); P1STEP(s2, w2); P1STEP(s3, w3);
        P1STEP(s4, w4); P1STEP(s5, w5); P1STEP(s6, w6); P1STEP(s7, w7);
    }
    for (; j + 4 <= end; j += 4) {
        int s0 = src[j], s1 = src[j + 1], s2 = src[j + 2], s3 = src[j + 3];
        float2 w0 = winv[s0], w1 = winv[s1], w2 = winv[s2], w3 = winv[s3];
        P1STEP(s0, w0); P1STEP(s1, w1); P1STEP(s2, w2); P1STEP(s3, w3);
    }
    for (; j < end; ++j) {
        int s = src[j]; float2 wv = winv[s];
        P1STEP(s, wv);
    }
#undef P1STEP
    // fp8 row-major for the next-hop gather (bytes: ao0,ao1,ai0,ai1,ao2,ao3,ai2,ai3)
    unsigned wa = (unsigned)__builtin_amdgcn_cvt_pk_fp8_f32(ao0, ao1, 0, false);
    wa = (unsigned)__builtin_amdgcn_cvt_pk_fp8_f32(ai0, ai1, wa, true);
    unsigned wb = (unsigned)__builtin_amdgcn_cvt_pk_fp8_f32(ao2, ao3, 0, false);
    wb = (unsigned)__builtin_amdgcn_cvt_pk_fp8_f32(ai2, ai3, wb, true);
    uint2 o8; o8.x = wa; o8.y = wb;
    *(uint2*)(P18 + (size_t)node * 256 + 8 * p) = o8;
    // bf16 fragments for the GEMM (unchanged precision)
    uint4 o;
    o.x = packbf(ao0, ao1); o.y = packbf(ai0, ai1);
    o.z = packbf(ao2, ao3); o.w = packbf(ai2, ai3);
    int tile = node >> 4, lr = node & 15, ck = p >> 2, q = p & 3;
    *(uint4*)(P1p + (((size_t)tile * 8 + ck) * 64 + q * 16 + lr) * 8) = o;
}

__global__ void prop2_128(const unsigned char* __restrict__ P18,
                          const unsigned short* __restrict__ Xc,
                          const int* __restrict__ rowptr, const int* __restrict__ src,
                          const float2* __restrict__ winv,
                          unsigned short* __restrict__ P2p, int n) {
    int tid = blockIdx.x * blockDim.x + threadIdx.x;
    int lane = tid & 63;
    int node = ((tid >> 6) << 1) + (lane >> 5);
    int p = lane & 31;
    if (node >= n) return;
    int beg = rowptr[node], end = rowptr[node + 1];
    float oa = 0.f, ob = 0.f, oc = 0.f, od = 0.f;
    float ia = 0.f, ib = 0.f, ic = 0.f, id = 0.f;
    int j = beg;
#define P2STEP(s_, w_) {                                                     \
        uint2 v = *(const uint2*)(P18 + (size_t)(s_) * 256 + 8 * p);         \
        f32x2 f0 = __builtin_amdgcn_cvt_pk_f32_fp8(v.x, false);              \
        f32x2 f1 = __builtin_amdgcn_cvt_pk_f32_fp8(v.x, true);               \
        f32x2 f2 = __builtin_amdgcn_cvt_pk_f32_fp8(v.y, false);              \
        f32x2 f3 = __builtin_amdgcn_cvt_pk_f32_fp8(v.y, true);               \
        oa = fmaf(w_.x, f0[0], oa); ob = fmaf(w_.x, f0[1], ob);              \
        ia = fmaf(w_.y, f1[0], ia); ib = fmaf(w_.y, f1[1], ib);              \
        oc = fmaf(w_.x, f2[0], oc); od = fmaf(w_.x, f2[1], od);              \
        ic = fmaf(w_.y, f3[0], ic); id = fmaf(w_.y, f3[1], id); }
    for (; j + 8 <= end; j += 8) {
        int s0 = src[j], s1 = src[j + 1], s2 = src[j + 2], s3 = src[j + 3];
        int s4 = src[j + 4], s5 = src[j + 5], s6 = src[j + 6], s7 = src[j + 7];
        float2 w0 = winv[s0], w1 = winv[s1], w2 = winv[s2], w3 = winv[s3];
        float2 w4 = winv[s4], w5 = winv[s5], w6 = winv[s6], w7 = winv[s7];
        P2STEP(s0, w0); P2STEP(s1, w1); P2STEP(s2, w2); P2STEP(s3, w3);
        P2STEP(s4, w4); P2STEP(s5, w5); P2STEP(s6, w6); P2STEP(s7, w7);
    }
    for (; j + 4 <= end; j += 4) {
        int s0 = src[j], s1 = src[j + 1], s2 = src[j + 2], s3 = src[j + 3];
        float2 w0 = winv[s0], w1 = winv[s1], w2 = winv[s2], w3 = winv[s3];
        P2STEP(s0, w0); P2STEP(s1, w1); P2STEP(s2, w2); P2STEP(s3, w3);
    }
    for (; j < end; ++j) {
        int s = src[j]; float2 wv = winv[s];
        P2STEP(s, wv);
    }
#undef P2STEP
    uint2 ux = *(const uint2*)(Xc + (size_t)node * 128 + 4 * p);
    float xa = bflo(ux.x), xb = bfhi(ux.x), xc = bflo(ux.y), xd = bfhi(ux.y);
    uint4 o;
    o.x = packbf(2.f * oa - xa, 2.f * ob - xb);
    o.y = packbf(2.f * ia - xa, 2.f * ib - xb);
    o.z = packbf(2.f * oc - xc, 2.f * od - xd);
    o.w = packbf(2.f * ic - xc, 2.f * id - xd);
    int tile = node >> 4, lr = node & 15, ck = p >> 2, q = p & 3;
    *(uint4*)(P2p + (((size_t)tile * 8 + ck) * 64 + q * 16 + lr) * 8) = o;
}

__global__ void prop1_64(const unsigned short* __restrict__ HR,
                         const int* __restrict__ rowptr, const int* __restrict__ src,
                         const float2* __restrict__ winv,
                         unsigned char* __restrict__ Q18, unsigned short* __restrict__ Q1p,
                         int n) {
    int tid = blockIdx.x * blockDim.x + threadIdx.x;
    int lane = tid & 63;
    int node = ((tid >> 6) << 2) + (lane >> 4);
    int p = lane & 15;
    if (node >= n) return;
    int beg = rowptr[node], end = rowptr[node + 1];
    float ao0 = 0.f, ao1 = 0.f, ao2 = 0.f, ao3 = 0.f;
    float ai0 = 0.f, ai1 = 0.f, ai2 = 0.f, ai3 = 0.f;
    int j = beg;
#define Q1STEP(s_, w_) {                                                     \
        uint2 u = *(const uint2*)(HR + (size_t)(s_) * 64 + 4 * p);           \
        float c0 = bflo(u.x), c1 = bfhi(u.x), c2 = bflo(u.y), c3 = bfhi(u.y);\
        ao0 = fmaf(w_.x, c0, ao0); ao1 = fmaf(w_.x, c1, ao1);                \
        ao2 = fmaf(w_.x, c2, ao2); ao3 = fmaf(w_.x, c3, ao3);                \
        ai0 = fmaf(w_.y, c0, ai0); ai1 = fmaf(w_.y, c1, ai1);                \
        ai2 = fmaf(w_.y, c2, ai2); ai3 = fmaf(w_.y, c3, ai3); }
    for (; j + 8 <= end; j += 8) {
        int s0 = src[j], s1 = src[j + 1], s2 = src[j + 2], s3 = src[j + 3];
        int s4 = src[j + 4], s5 = src[j + 5], s6 = src[j + 6], s7 = src[j + 7];
        float2 w0 = winv[s0], w1 = winv[s1], w2 = winv[s2], w3 = winv[s3];
        float2 w4 = winv[s4], w5 = winv[s5], w6 = winv[s6], w7 = winv[s7];
        Q1STEP(s0, w0); Q1STEP(s1, w1); Q1STEP(s2, w2); Q1STEP(s3, w3);
        Q1STEP(s4, w4); Q1STEP(s5, w5); Q1STEP(s6, w6); Q1STEP(s7, w7);
    }
    for (; j + 4 <= end; j += 4) {
        int s0 = src[j], s1 = src[j + 1], s2 = src[j + 2], s3 = src[j + 3];
        float2 w0 = winv[s0], w1 = winv[s1], w2 = winv[s2], w3 = winv[s3];
        Q1STEP(s0, w0); Q1STEP(s1, w1); Q1STEP(s2, w2); Q1STEP(s3, w3);
    }
    for (; j < end; ++j) {
        int s = src[j]; float2 wv = winv[s];
        Q1STEP(s, wv);
    }
#undef Q1STEP
    unsigned wa = (unsigned)__builtin_amdgcn_cvt_pk_fp8_f32(ao0, ao1, 0, false);
    wa = (unsigned)__builtin_amdgcn_cvt_pk_fp8_f32(ai0, ai1, wa, true);
    unsigned wb = (unsigned)__builtin_amdgcn_cvt_pk_fp8_f32(ao2, ao3, 0, false);
    wb = (unsigned)__builtin_amdgcn_cvt_pk_fp8_f32(ai2, ai3, wb, true);
    uint2 o8; o8.x = wa; o8.y = wb;
    *(uint2*)(Q18 + (size_t)node * 128 + 8 * p) = o8;
    uint4 o;
    o.x = packbf(ao0, ao1); o.y = packbf(ai0, ai1);
    o.z = packbf(ao2, ao3); o.w = packbf(ai2, ai3);
    int tile = node >> 4, lr = node & 15, ck = p >> 2, q = p & 3;
    *(uint4*)(Q1p + (((size_t)tile * 4 + ck) * 64 + q * 16 + lr) * 8) = o;
}

__global__ void prop2_64(const unsigned char* __restrict__ Q18,
                         const unsigned short* __restrict__ HR,
                         const int* __restrict__ rowptr, const int* __restrict__ src,
                         const float2* __restrict__ winv,
                         unsigned short* __restrict__ Q2p, int n) {
    int tid = blockIdx.x * blockDim.x + threadIdx.x;
    int lane = tid & 63;
    int node = ((tid >> 6) << 2) + (lane >> 4);
    int p = lane & 15;
    if (node >= n) return;
    int beg = rowptr[node], end = rowptr[node + 1];
    float oa = 0.f, ob = 0.f, oc = 0.f, od = 0.f;
    float ia = 0.f, ib = 0.f, ic = 0.f, id = 0.f;
    int j = beg;
#define Q2STEP(s_, w_) {                                                     \
        uint2 v = *(const uint2*)(Q18 + (size_t)(s_) * 128 + 8 * p);         \
        f32x2 f0 = __builtin_amdgcn_cvt_pk_f32_fp8(v.x, false);              \
        f32x2 f1 = __builtin_amdgcn_cvt_pk_f32_fp8(v.x, true);               \
        f32x2 f2 = __builtin_amdgcn_cvt_pk_f32_fp8(v.y, false);              \
        f32x2 f3 = __builtin_amdgcn_cvt_pk_f32_fp8(v.y, true);               \
        oa = fmaf(w_.x, f0[0], oa); ob = fmaf(w_.x, f0[1], ob);              \
        ia = fmaf(w_.y, f1[0], ia); ib = fmaf(w_.y, f1[1], ib);              \
        oc = fmaf(w_.x, f2[0], oc); od = fmaf(w_.x, f2[1], od);              \
        ic = fmaf(w_.y, f3[0], ic); id = fmaf(w_.y, f3[1], id); }
    for (; j + 8 <= end; j += 8) {
        int s0 = src[j], s1 = src[j + 1], s2 = src[j + 2], s3 = src[j + 3];
        int s4 = src[j + 4], s5 = src[j + 5], s6 = src[j + 6], s7 = src[j + 7];
        float2 w0 = winv[s0], w1 = winv[s1], w2 = winv[s2], w3 = winv[s3];
        float2 w4 = winv[s4], w5 = winv[s5], w6 = winv[s6], w7 = winv[s7];
        Q2STEP(s0, w0); Q2STEP(s1, w1); Q2STEP(s2, w2); Q2STEP(s3, w3);
        Q2STEP(s4, w4); Q2STEP(s5, w5); Q2STEP(s6, w6); Q2STEP(s7, w7);
    }
    for (; j + 4 <= end; j += 4) {
        int s0 = src[j], s1 = src[j + 1], s2 = src[j + 2], s3 = src[j + 3];
        float2 w0 = winv[s0], w1 = winv[s1], w2 = winv[s2], w3 = winv[s3];
        Q2STEP(s0, w0); Q2STEP(s1, w1); Q2STEP(s2, w2); Q2STEP(s3, w3);
    }
    for (; j < end; ++j) {
        int s = src[j]; float2 wv = winv[s];
        Q2STEP(s, wv);
    }
#undef Q2STEP
    uint2 ux = *(const uint2*)(HR + (size_t)node * 64 + 4 * p);
    float xa = bflo(ux.x), xb = bfhi(ux.x), xc = bflo(ux.y), xd = bfhi(ux.y);
    uint4 o;
    o.x = packbf(2.f * oa - xa, 2.f * ob - xb);
    o.y = packbf(2.f * ia - xa, 2.f * ib - xb);
    o.z = packbf(2.f * oc - xc, 2.f * od - xd);
    o.w = packbf(2.f * ic - xc, 2.f * id - xd);
    int tile = node >> 4, lr = node & 15, ck = p >> 2, q = p & 3;
    *(uint4*)(Q2p + (((size_t)tile * 4 + ck) * 64 + q * 16 + lr) * 8) = o;
}

// ---------------- MFMA GEMMs: fragment-packed A and B, no LDS, no barriers --
// All frag loads are coalesced 1KB wave loads: lane i reads 16B at base+16i.
// mfma_f32_16x16x32_bf16 C/D: col=lane&15, row=(lane>>4)*4+reg.
// v2: small per-wave tiles for occupancy + 1-deep register prefetch on ks.

// ZR: block 32 rows x 128 cols; 4 waves each 32 rows x 32 cols (ngrp = wid).
__global__ __launch_bounds__(256) void gemm_zr_mfma(
    const unsigned short* __restrict__ XHp, const unsigned short* __restrict__ P1p,
    const unsigned short* __restrict__ P2p,
    const unsigned short* __restrict__ Wf, const float* bz,
    const float* br, const float* __restrict__ H,
    float* __restrict__ Zf, unsigned short* __restrict__ HR, int n) {
    int tid = threadIdx.x;
    int lane = tid & 63;
    int ngrp = tid >> 6;
    int rowbase = blockIdx.x * 32;
    int lr = lane & 15, quad = lane >> 4;

    int tiles[2];
#pragma unroll
    for (int mt = 0; mt < 2; ++mt) {
        int t = (rowbase >> 4) + mt;
        tiles[mt] = (t > N_TILES - 1) ? N_TILES - 1 : t;
    }

    auto LDB = [&](int ks, int nt) {
        return *(const bf8*)(Wf + (((size_t)ks * 8 + ngrp * 2 + nt) * 64 + lane) * 8);
    };
    auto LDA = [&](int ks, int mt) {
        const unsigned short* T = (ks < 4) ? XHp : (ks < 12) ? P1p : P2p;
        int ck = (ks < 4) ? ks : (ks < 12) ? ks - 4 : ks - 12;
        int nck = (ks < 4) ? 4 : 8;
        return *(const bf8*)(T + (((size_t)tiles[mt] * nck + ck) * 64 + lane) * 8);
    };

    f32x4 zero = {0.f, 0.f, 0.f, 0.f};
    f32x4 acc[2][2];
#pragma unroll
    for (int a = 0; a < 2; ++a)
#pragma unroll
        for (int b = 0; b < 2; ++b) acc[a][b] = zero;

    bf8 a0 = LDA(0, 0), a1 = LDA(0, 1), b0 = LDB(0, 0), b1 = LDB(0, 1);
#pragma unroll
    for (int ks = 0; ks < 20; ++ks) {
        bf8 na0, na1, nb0, nb1;
        if (ks < 19) {
            na0 = LDA(ks + 1, 0); na1 = LDA(ks + 1, 1);
            nb0 = LDB(ks + 1, 0); nb1 = LDB(ks + 1, 1);
        }
        acc[0][0] = __builtin_amdgcn_mfma_f32_16x16x32_bf16(a0, b0, acc[0][0], 0, 0, 0);
        acc[0][1] = __builtin_amdgcn_mfma_f32_16x16x32_bf16(a0, b1, acc[0][1], 0, 0, 0);
        acc[1][0] = __builtin_amdgcn_mfma_f32_16x16x32_bf16(a1, b0, acc[1][0], 0, 0, 0);
        acc[1][1] = __builtin_amdgcn_mfma_f32_16x16x32_bf16(a1, b1, acc[1][1], 0, 0, 0);
        if (ks < 19) { a0 = na0; a1 = na1; b0 = nb0; b1 = nb1; }
    }
#pragma unroll
    for (int mt = 0; mt < 2; ++mt)
#pragma unroll
        for (int reg = 0; reg < 4; ++reg) {
            int r = rowbase + mt * 16 + quad * 4 + reg;
            if (r >= n) continue;
#pragma unroll
            for (int nt = 0; nt < 2; ++nt) {
                int cidx = ngrp * 32 + nt * 16 + lr;
                float bias = (cidx < 64) ? bz[cidx] : br[cidx - 64];
                float v = acc[mt][nt][reg] + bias;
                float s = 1.f / (1.f + expf(-v));
                if (cidx < 64) {
                    Zf[(size_t)r * 64 + cidx] = s;
                } else {
                    int c2 = cidx - 64;
                    HR[(size_t)r * 64 + c2] = f2bfu(H[(size_t)r * 64 + c2] * s);
                }
            }
        }
}

// H~: block 32 rows x 64 cols; 4 waves = (mh = wid&1 row-tile, ngrp = wid>>1),
// each 16 rows x 32 cols. ks: 0-1 XHp, 2-5 P1p, 6-9 P2p(X-half), 10-11 HR
// (row-major strided), 12-15 Q1p, 16-19 Q2p.
__global__ __launch_bounds__(256) void gemm_h_mfma(
    const unsigned short* __restrict__ XHp, const unsigned short* __restrict__ P1p,
    const unsigned short* __restrict__ P2p, const unsigned short* __restrict__ HR,
    const unsigned short* __restrict__ Q1p, const unsigned short* __restrict__ Q2p,
    const unsigned short* __restrict__ Wf, const float* bh,
    const float* __restrict__ Zf, const float* __restrict__ H,
    float* __restrict__ out, int n) {
    int tid = threadIdx.x;
    int lane = tid & 63;
    int wid = tid >> 6;
    int mh = wid & 1, ngrp = wid >> 1;
    int rowbase = blockIdx.x * 32 + mh * 16;
    int lr = lane & 15, quad = lane >> 4;

    int t = rowbase >> 4;
    int tile = (t > N_TILES - 1) ? N_TILES - 1 : t;
    int rh = rowbase + lr;
    if (rh >= n) rh = n - 1;
    const unsigned short* hrp = HR + (size_t)rh * 64 + quad * 8;

    auto LDB = [&](int ks, int nt) {
        return *(const bf8*)(Wf + (((size_t)ks * 4 + ngrp * 2 + nt) * 64 + lane) * 8);
    };
    auto LDA = [&](int ks) {
        if (ks == 10 || ks == 11) {
            return *(const bf8*)(hrp + (ks - 10) * 32);
        }
        const unsigned short* T = (ks < 2) ? XHp : (ks < 6) ? P1p :
                                  (ks < 10) ? P2p : (ks < 16) ? Q1p : Q2p;
        int ck = (ks < 2) ? ks : (ks < 6) ? ks - 2 : (ks < 10) ? ks - 6 :
                 (ks < 16) ? ks - 12 : ks - 16;
        int nck = (ks < 2) ? 4 : (ks < 10) ? 8 : 4;
        return *(const bf8*)(T + (((size_t)tile * nck + ck) * 64 + lane) * 8);
    };

    f32x4 zero = {0.f, 0.f, 0.f, 0.f};
    f32x4 acc[2];
    acc[0] = zero; acc[1] = zero;

    bf8 a0 = LDA(0), b0 = LDB(0, 0), b1 = LDB(0, 1);
#pragma unroll
    for (int ks = 0; ks < 20; ++ks) {
        bf8 na0, nb0, nb1;
        if (ks < 19) {
            na0 = LDA(ks + 1); nb0 = LDB(ks + 1, 0); nb1 = LDB(ks + 1, 1);
        }
        acc[0] = __builtin_amdgcn_mfma_f32_16x16x32_bf16(a0, b0, acc[0], 0, 0, 0);
        acc[1] = __builtin_amdgcn_mfma_f32_16x16x32_bf16(a0, b1, acc[1], 0, 0, 0);
        if (ks < 19) { a0 = na0; b0 = nb0; b1 = nb1; }
    }
#pragma unroll
    for (int reg = 0; reg < 4; ++reg) {
        int r = rowbase + quad * 4 + reg;
        if (r >= n) continue;
#pragma unroll
        for (int nt = 0; nt < 2; ++nt) {
            int cidx = ngrp * 32 + nt * 16 + lr;
            float ht = tanhf(acc[nt][reg] + bh[cidx]);
            float z = Zf[(size_t)r * 64 + cidx];
            float h_old = H[(size_t)r * 64 + cidx];
            out[(size_t)r * 64 + cidx] = z * h_old + (1.f - z) * ht;
        }
    }
}

// ---------------- launch ----------------

static inline size_t rup(size_t x) { return (x + 63) & ~(size_t)63; }

extern "C" void kernel_launch(void* const* d_in, const int* in_sizes, int n_in,
                              void* d_out, int out_size, void* d_ws, size_t ws_size,
                              hipStream_t stream) {
    const float* X  = (const float*)d_in[0];
    const int*   EI = (const int*)d_in[1];
    const float* H  = (const float*)d_in[2];
    const float* Wz = (const float*)d_in[3];
    const float* bz = (const float*)d_in[4];
    const float* Wr = (const float*)d_in[5];
    const float* br = (const float*)d_in[6];
    const float* Wh = (const float*)d_in[7];
    const float* bh = (const float*)d_in[8];
    float* out = (float*)d_out;

    const int* row = EI;
    const int* col = EI + N_EDGES;

    char* ws = (char*)d_ws;
    size_t off = 0;
    auto carve = [&](size_t bytes) { void* p = ws + off; off += rup(bytes); return p; };

    int*   deg_out   = (int*)carve(N_NODES * 4);
    int*   deg_in    = (int*)carve(N_NODES * 4);
    int*   rowptr    = (int*)carve((N_NODES + 1) * 4);
    int*   cursor    = (int*)carve(N_NODES * 4);
    int*   blocksums = (int*)carve(64 * 4);
    float2* winv     = (float2*)carve(N_NODES * 8);
    int*   csr_src   = (int*)carve(N_EDGES * 4);
    unsigned short* XH  = (unsigned short*)carve((size_t)N_NODES * 128 * 2);  // dead after prop2_128
    unsigned char*  Pscr = (unsigned char*)carve((size_t)N_NODES * 256 + (size_t)N_TILES * 4 * 512 * 2);
    unsigned short* XHp = (unsigned short*)carve((size_t)N_TILES * 4 * 512 * 2);
    unsigned short* P1p = (unsigned short*)carve((size_t)N_TILES * 8 * 512 * 2);
    unsigned short* P2p = (unsigned short*)carve((size_t)N_TILES * 8 * 512 * 2);
    unsigned short* HR  = (unsigned short*)carve((size_t)N_NODES * 64 * 2);
    float* Zf           = (float*)carve((size_t)N_NODES * 64 * 4);
    unsigned short* Wzrf = (unsigned short*)carve(20 * 8 * 64 * 8 * 2);
    unsigned short* Whf  = (unsigned short*)carve(20 * 4 * 64 * 8 * 2);

    // P18 fp8 [n][256] lives in Pscr; dead after prop2_128, then Q1p/Q2p overlay it.
    unsigned char*  P18 = Pscr;                                // 12.8 MB fp8
    unsigned char*  Q18 = (unsigned char*)XH;                  // 6.4 MB fp8 (XH dead after prop2_128)
    unsigned short* Q1p = (unsigned short*)Pscr;               // 12.8 MB bf16 fragments
    unsigned short* Q2p = (unsigned short*)(Pscr + (size_t)N_NODES * 256);  // 12.8 MB

    hipMemsetAsync(deg_out, 0, rup(N_NODES * 4) + rup(N_NODES * 4), stream);
    count_deg<<<(N_EDGES + 255) / 256, 256, 0, stream>>>(row, col, deg_out, deg_in, N_EDGES);

    int nblk = (N_NODES + 1023) / 1024;
    scan_block<<<nblk, 1024, 0, stream>>>(deg_in, rowptr, blocksums, N_NODES);
    scan_sums<<<1, 64, 0, stream>>>(blocksums, nblk);
    scan_add<<<(N_NODES + 1 + 255) / 256, 256, 0, stream>>>(rowptr, blocksums, cursor,
                                                            deg_out, deg_in, winv, N_NODES, N_EDGES);

    // fused: build_csr + concat_xh + pack_weights
    fused_prep<<<CSR_BLOCKS + CONCAT_BLOCKS + PACK_BLOCKS, 256, 0, stream>>>(
        row, col, cursor, csr_src,
        X, H, XH, XHp, Wz, Wr, Wh, Wzrf, Whf, N_NODES, N_EDGES);

    // props on XH: 2 nodes/wave
    int blocks_p128 = (((N_NODES + 1) / 2) * 64 + 255) / 256;
    prop1_128<<<blocks_p128, 256, 0, stream>>>(XH, rowptr, csr_src, winv, P18, P1p, N_NODES);
    prop2_128<<<blocks_p128, 256, 0, stream>>>(P18, XH, rowptr, csr_src, winv, P2p, N_NODES);

    // Z|R GEMM -> Zf, HR   (XH, P18 now dead)
    int zr_blocks = (N_NODES + 31) / 32;
    gemm_zr_mfma<<<zr_blocks, 256, 0, stream>>>(XHp, P1p, P2p, Wzrf, bz, br, H, Zf, HR, N_NODES);

    // props on HR: 4 nodes/wave
    int blocks_p64 = (((N_NODES + 3) / 4) * 64 + 255) / 256;
    prop1_64<<<blocks_p64, 256, 0, stream>>>(HR, rowptr, csr_src, winv, Q18, Q1p, N_NODES);
    prop2_64<<<blocks_p64, 256, 0, stream>>>(Q18, HR, rowptr, csr_src, winv, Q2p, N_NODES);

    // H~ GEMM + GRU mix -> out
    int h_blocks = (N_NODES + 31) / 32;
    gemm_h_mfma<<<h_blocks, 256, 0, stream>>>(XHp, P1p, P2p, HR, Q1p, Q2p,
                                              Whf, bh, Zf, H, out, N_NODES);
}

// Round 5
// 324.177 us; speedup vs baseline: 1.1229x; 1.0145x over previous
//
#include <hip/hip_runtime.h>
#include <hip/hip_bf16.h>
#include <math.h>

#define N_NODES 50000
#define N_EDGES 500000
#define C_DIM 128
#define N_TILES 3125   // 50000/16 exact

#define CSR_BLOCKS 489       // ceil(500000/1024): 4 edges/thread
#define CONCAT_BLOCKS 3125   // 50000*16/256
#define PACK_BLOCKS 480      // (20*8*512 + 20*4*512)/256

typedef __attribute__((ext_vector_type(8))) short bf8;
typedef __attribute__((ext_vector_type(4))) float f32x4;
typedef __attribute__((ext_vector_type(2))) float f32x2;

__device__ __forceinline__ float bflo(unsigned u) { return __uint_as_float(u << 16); }
__device__ __forceinline__ float bfhi(unsigned u) { return __uint_as_float(u & 0xffff0000u); }
__device__ __forceinline__ unsigned short f2bfu(float f) {
    __hip_bfloat16 h = __float2bfloat16(f);
    unsigned short u;
    __builtin_memcpy(&u, &h, 2);
    return u;
}
__device__ __forceinline__ unsigned packbf(float a, float b) {
    return ((unsigned)f2bfu(b) << 16) | f2bfu(a);
}

// ---------------- graph preprocessing ----------------

__global__ void count_deg(const int* __restrict__ row, const int* __restrict__ col,
                          int* __restrict__ dout, int* __restrict__ din, int e) {
    int i = blockIdx.x * blockDim.x + threadIdx.x;
    if (i >= e) return;
    atomicAdd(&dout[row[i]], 1);
    atomicAdd(&din[col[i]], 1);
}

__global__ void scan_block(const int* __restrict__ counts, int* __restrict__ excl,
                           int* __restrict__ blocksums, int n) {
    __shared__ int tmp[1024];
    int tid = threadIdx.x;
    int gid = blockIdx.x * 1024 + tid;
    int v = (gid < n) ? counts[gid] : 0;
    tmp[tid] = v;
    __syncthreads();
    for (int off = 1; off < 1024; off <<= 1) {
        int t = (tid >= off) ? tmp[tid - off] : 0;
        __syncthreads();
        tmp[tid] += t;
        __syncthreads();
    }
    int incl = tmp[tid];
    if (gid < n) excl[gid] = incl - v;
    if (tid == 1023) blocksums[blockIdx.x] = incl;
}

__global__ void scan_sums(int* __restrict__ blocksums, int nb) {
    __shared__ int tmp[64];
    int tid = threadIdx.x;
    int v = (tid < nb) ? blocksums[tid] : 0;
    tmp[tid] = v;
    __syncthreads();
    for (int off = 1; off < 64; off <<= 1) {
        int t = (tid >= off) ? tmp[tid - off] : 0;
        __syncthreads();
        tmp[tid] += t;
        __syncthreads();
    }
    if (tid < nb) blocksums[tid] = tmp[tid] - v;
}

__global__ void scan_add(int* __restrict__ rowptr, const int* __restrict__ blocksums,
                         int* __restrict__ cursor, const int* __restrict__ dout,
                         const int* __restrict__ din, float2* __restrict__ winv,
                         int n, int e_total) {
    int gid = blockIdx.x * blockDim.x + threadIdx.x;
    if (gid < n) {
        int v = rowptr[gid] + blocksums[gid >> 10];
        rowptr[gid] = v;
        cursor[gid] = v;
        winv[gid] = make_float2(1.0f / (float)dout[gid], 1.0f / (float)din[gid]);
    }
    if (gid == n) rowptr[n] = e_total;
}

// ---------------- weight helpers ----------------
__device__ __forceinline__ float wraw(const float* W, int d, int kk, int k, int j) {
    return W[((d * 3 + kk) * 128 + k) * 64 + j];
}

__device__ __forceinline__ float zr_val(const float* Wz, const float* Wr, int k, int nn) {
    const float* W = (nn < 64) ? Wz : Wr;
    int j = nn & 63;
    if (k < 128) return wraw(W, 0, 0, k, j) + wraw(W, 1, 0, k, j);
    int k2 = k - 128;
    int kk = (k2 >= 256) ? 2 : 1;
    int k3 = k2 & 255;
    int p = k3 >> 2, sub = k3 & 3;
    return wraw(W, sub >> 1, kk, 2 * p + (sub & 1), j);
}

__device__ __forceinline__ float h_val(const float* Wh, int k, int j) {
    if (k < 64) return wraw(Wh, 0, 0, k, j) + wraw(Wh, 1, 0, k, j);
    if (k < 320) {
        int k2 = k - 64;
        int kk = (k2 >= 128) ? 2 : 1;
        int k3 = k2 & 127;
        int p = k3 >> 2, sub = k3 & 3;
        return wraw(Wh, sub >> 1, kk, 2 * p + (sub & 1), j);
    }
    if (k < 384) return wraw(Wh, 0, 0, 64 + (k - 320), j) + wraw(Wh, 1, 0, 64 + (k - 320), j);
    int k2 = k - 384;
    int kk = (k2 >= 128) ? 2 : 1;
    int k3 = k2 & 127;
    int p = k3 >> 2, sub = k3 & 3;
    return wraw(Wh, sub >> 1, kk, 64 + 2 * p + (sub & 1), j);
}

// ---------------- fused prep: build_csr + concat_xh + pack_weights ----------
// CSR carries ONLY src ids (4B scatter per edge). Edge weights are gathered
// as winv[src] inside the props (winv = 400KB, L2-resident).
// CSR branch: 4 independent edge chains per thread (latency hiding).
__global__ void fused_prep(const int* __restrict__ row, const int* __restrict__ col,
                           int* __restrict__ cursor,
                           int* __restrict__ csr_src,
                           const float* __restrict__ X, const float* __restrict__ Hm,
                           unsigned short* __restrict__ XH, unsigned short* __restrict__ XHp,
                           const float* Wz, const float* Wr,
                           const float* Wh,
                           unsigned short* __restrict__ Wzrf, unsigned short* __restrict__ Whf,
                           int n, int e) {
    int b = blockIdx.x;
    if (b < CSR_BLOCKS) {
        int base = b * 1024 + threadIdx.x;
#pragma unroll
        for (int k = 0; k < 4; ++k) {
            int i = base + k * 256;
            if (i < e) {
                int r = row[i], c = col[i];
                int pos = atomicAdd(&cursor[c], 1);
                csr_src[pos] = r;
            }
        }
    } else if (b < CSR_BLOCKS + CONCAT_BLOCKS) {
        int t = (b - CSR_BLOCKS) * 256 + threadIdx.x;   // < n*16 exactly
        int node = t >> 4, p = t & 15;
        const float* src = (p < 8) ? (X + (size_t)node * 64 + 8 * p)
                                   : (Hm + (size_t)node * 64 + 8 * (p - 8));
        float4 v0 = *(const float4*)src;
        float4 v1 = *(const float4*)(src + 4);
        uint4 o;
        o.x = packbf(v0.x, v0.y); o.y = packbf(v0.z, v0.w);
        o.z = packbf(v1.x, v1.y); o.w = packbf(v1.z, v1.w);
        *(uint4*)(XH + (size_t)node * 128 + 8 * p) = o;
        int tile = node >> 4, lr = node & 15, ck = p >> 2, q = p & 3;
        *(uint4*)(XHp + (((size_t)tile * 4 + ck) * 64 + q * 16 + lr) * 8) = o;
    } else {
        int i = (b - CSR_BLOCKS - CONCAT_BLOCKS) * 256 + threadIdx.x;
        if (i < 20 * 8 * 64 * 8) {
            int j = i & 7, lane = (i >> 3) & 63, nt = (i >> 9) & 7, ks = i >> 12;
            int k = ks * 32 + (lane >> 4) * 8 + j;
            int nn = nt * 16 + (lane & 15);
            Wzrf[i] = f2bfu(zr_val(Wz, Wr, k, nn));
        } else if (i < 20 * 8 * 64 * 8 + 20 * 4 * 64 * 8) {
            int i2 = i - 20 * 8 * 64 * 8;
            int j = i2 & 7, lane = (i2 >> 3) & 63, nt = (i2 >> 9) & 3, ks = i2 >> 11;
            int k = ks * 32 + (lane >> 4) * 8 + j;
            int nn = nt * 16 + (lane & 15);
            Whf[i2] = f2bfu(h_val(Wh, k, nn));
        }
    }
}

// ---------------- diffusion props ----------------
// Hop-1 gathers read bf16 (XH / HR). Hop-2 gathers read fp8 (P18 / Q18) —
// measured: hop-2 fp8 costs +0.040 absmax; hop-1 fp8 cost +0.098 (rejected).
// Packed: T[tile][ck][lane][8] bf16. fp8 = OCP e4m3 via HW cvt.
// Edge weight = winv[src] gathered on the fly (L2-resident).

__global__ void prop1_128(const unsigned short* __restrict__ S,
                          const int* __restrict__ rowptr, const int* __restrict__ src,
                          const float2* __restrict__ winv,
                          unsigned char* __restrict__ P18, unsigned short* __restrict__ P1p,
                          int n) {
    int tid = blockIdx.x * blockDim.x + threadIdx.x;
    int lane = tid & 63;
    int node = ((tid >> 6) << 1) + (lane >> 5);
    int p = lane & 31;
    if (node >= n) return;
    int beg = rowptr[node], end = rowptr[node + 1];
    float ao0 = 0.f, ao1 = 0.f, ao2 = 0.f, ao3 = 0.f;
    float ai0 = 0.f, ai1 = 0.f, ai2 = 0.f, ai3 = 0.f;
    int j = beg;
#define P1STEP(s_, w_) {                                                     \
        uint2 u = *(const uint2*)(S + (size_t)(s_) * 128 + 4 * p);           \
        float c0 = bflo(u.x), c1 = bfhi(u.x), c2 = bflo(u.y), c3 = bfhi(u.y);\
        ao0 = fmaf(w_.x, c0, ao0); ao1 = fmaf(w_.x, c1, ao1);                \
        ao2 = fmaf(w_.x, c2, ao2); ao3 = fmaf(w_.x, c3, ao3);                \
        ai0 = fmaf(w_.y, c0, ai0); ai1 = fmaf(w_.y, c1, ai1);                \
        ai2 = fmaf(w_.y, c2, ai2); ai3 = fmaf(w_.y, c3, ai3); }
    for (; j + 8 <= end; j += 8) {
        int s0 = src[j], s1 = src[j + 1], s2 = src[j + 2], s3 = src[j + 3];
        int s4 = src[j + 4], s5 = src[j + 5], s6 = src[j + 6], s7 = src[j + 7];
        float2 w0 = winv[s0], w1 = winv[s1], w2 = winv[s2], w3 = winv[s3];
        float2 w4 = winv[s4], w5 = winv[s5], w6 = winv[s6], w7 = winv[s7];
        P1STEP(s0, w0); P1STEP(s1, w1); P1STEP(s2, w2); P1STEP(s3, w3);
        P1STEP(s4, w4); P1STEP(s5, w5); P1STEP(s6, w6); P1STEP(s7, w7);
    }
    for (; j + 4 <= end; j += 4) {
        int s0 = src[j], s1 = src[j + 1], s2 = src[j + 2], s3 = src[j + 3];
        float2 w0 = winv[s0], w1 = winv[s1], w2 = winv[s2], w3 = winv[s3];
        P1STEP(s0, w0); P1STEP(s1, w1); P1STEP(s2, w2); P1STEP(s3, w3);
    }
    for (; j < end; ++j) {
        int s = src[j]; float2 wv = winv[s];
        P1STEP(s, wv);
    }
#undef P1STEP
    // fp8 row-major for the next-hop gather (bytes: ao0,ao1,ai0,ai1,ao2,ao3,ai2,ai3)
    unsigned wa = (unsigned)__builtin_amdgcn_cvt_pk_fp8_f32(ao0, ao1, 0, false);
    wa = (unsigned)__builtin_amdgcn_cvt_pk_fp8_f32(ai0, ai1, wa, true);
    unsigned wb = (unsigned)__builtin_amdgcn_cvt_pk_fp8_f32(ao2, ao3, 0, false);
    wb = (unsigned)__builtin_amdgcn_cvt_pk_fp8_f32(ai2, ai3, wb, true);
    uint2 o8; o8.x = wa; o8.y = wb;
    *(uint2*)(P18 + (size_t)node * 256 + 8 * p) = o8;
    // bf16 fragments for the GEMM (unchanged precision)
    uint4 o;
    o.x = packbf(ao0, ao1); o.y = packbf(ai0, ai1);
    o.z = packbf(ao2, ao3); o.w = packbf(ai2, ai3);
    int tile = node >> 4, lr = node & 15, ck = p >> 2, q = p & 3;
    *(uint4*)(P1p + (((size_t)tile * 8 + ck) * 64 + q * 16 + lr) * 8) = o;
}

__global__ void prop2_128(const unsigned char* __restrict__ P18,
                          const unsigned short* __restrict__ Xc,
                          const int* __restrict__ rowptr, const int* __restrict__ src,
                          const float2* __restrict__ winv,
                          unsigned short* __restrict__ P2p, int n) {
    int tid = blockIdx.x * blockDim.x + threadIdx.x;
    int lane = tid & 63;
    int node = ((tid >> 6) << 1) + (lane >> 5);
    int p = lane & 31;
    if (node >= n) return;
    int beg = rowptr[node], end = rowptr[node + 1];
    float oa = 0.f, ob = 0.f, oc = 0.f, od = 0.f;
    float ia = 0.f, ib = 0.f, ic = 0.f, id = 0.f;
    int j = beg;
#define P2STEP(s_, w_) {                                                     \
        uint2 v = *(const uint2*)(P18 + (size_t)(s_) * 256 + 8 * p);         \
        f32x2 f0 = __builtin_amdgcn_cvt_pk_f32_fp8(v.x, false);              \
        f32x2 f1 = __builtin_amdgcn_cvt_pk_f32_fp8(v.x, true);               \
        f32x2 f2 = __builtin_amdgcn_cvt_pk_f32_fp8(v.y, false);              \
        f32x2 f3 = __builtin_amdgcn_cvt_pk_f32_fp8(v.y, true);               \
        oa = fmaf(w_.x, f0[0], oa); ob = fmaf(w_.x, f0[1], ob);              \
        ia = fmaf(w_.y, f1[0], ia); ib = fmaf(w_.y, f1[1], ib);              \
        oc = fmaf(w_.x, f2[0], oc); od = fmaf(w_.x, f2[1], od);              \
        ic = fmaf(w_.y, f3[0], ic); id = fmaf(w_.y, f3[1], id); }
    for (; j + 8 <= end; j += 8) {
        int s0 = src[j], s1 = src[j + 1], s2 = src[j + 2], s3 = src[j + 3];
        int s4 = src[j + 4], s5 = src[j + 5], s6 = src[j + 6], s7 = src[j + 7];
        float2 w0 = winv[s0], w1 = winv[s1], w2 = winv[s2], w3 = winv[s3];
        float2 w4 = winv[s4], w5 = winv[s5], w6 = winv[s6], w7 = winv[s7];
        P2STEP(s0, w0); P2STEP(s1, w1); P2STEP(s2, w2); P2STEP(s3, w3);
        P2STEP(s4, w4); P2STEP(s5, w5); P2STEP(s6, w6); P2STEP(s7, w7);
    }
    for (; j + 4 <= end; j += 4) {
        int s0 = src[j], s1 = src[j + 1], s2 = src[j + 2], s3 = src[j + 3];
        float2 w0 = winv[s0], w1 = winv[s1], w2 = winv[s2], w3 = winv[s3];
        P2STEP(s0, w0); P2STEP(s1, w1); P2STEP(s2, w2); P2STEP(s3, w3);
    }
    for (; j < end; ++j) {
        int s = src[j]; float2 wv = winv[s];
        P2STEP(s, wv);
    }
#undef P2STEP
    uint2 ux = *(const uint2*)(Xc + (size_t)node * 128 + 4 * p);
    float xa = bflo(ux.x), xb = bfhi(ux.x), xc = bflo(ux.y), xd = bfhi(ux.y);
    uint4 o;
    o.x = packbf(2.f * oa - xa, 2.f * ob - xb);
    o.y = packbf(2.f * ia - xa, 2.f * ib - xb);
    o.z = packbf(2.f * oc - xc, 2.f * od - xd);
    o.w = packbf(2.f * ic - xc, 2.f * id - xd);
    int tile = node >> 4, lr = node & 15, ck = p >> 2, q = p & 3;
    *(uint4*)(P2p + (((size_t)tile * 8 + ck) * 64 + q * 16 + lr) * 8) = o;
}

__global__ void prop1_64(const unsigned short* __restrict__ HR,
                         const int* __restrict__ rowptr, const int* __restrict__ src,
                         const float2* __restrict__ winv,
                         unsigned char* __restrict__ Q18, unsigned short* __restrict__ Q1p,
                         int n) {
    int tid = blockIdx.x * blockDim.x + threadIdx.x;
    int lane = tid & 63;
    int node = ((tid >> 6) << 2) + (lane >> 4);
    int p = lane & 15;
    if (node >= n) return;
    int beg = rowptr[node], end = rowptr[node + 1];
    float ao0 = 0.f, ao1 = 0.f, ao2 = 0.f, ao3 = 0.f;
    float ai0 = 0.f, ai1 = 0.f, ai2 = 0.f, ai3 = 0.f;
    int j = beg;
#define Q1STEP(s_, w_) {                                                     \
        uint2 u = *(const uint2*)(HR + (size_t)(s_) * 64 + 4 * p);           \
        float c0 = bflo(u.x), c1 = bfhi(u.x), c2 = bflo(u.y), c3 = bfhi(u.y);\
        ao0 = fmaf(w_.x, c0, ao0); ao1 = fmaf(w_.x, c1, ao1);                \
        ao2 = fmaf(w_.x, c2, ao2); ao3 = fmaf(w_.x, c3, ao3);                \
        ai0 = fmaf(w_.y, c0, ai0); ai1 = fmaf(w_.y, c1, ai1);                \
        ai2 = fmaf(w_.y, c2, ai2); ai3 = fmaf(w_.y, c3, ai3); }
    for (; j + 8 <= end; j += 8) {
        int s0 = src[j], s1 = src[j + 1], s2 = src[j + 2], s3 = src[j + 3];
        int s4 = src[j + 4], s5 = src[j + 5], s6 = src[j + 6], s7 = src[j + 7];
        float2 w0 = winv[s0], w1 = winv[s1], w2 = winv[s2], w3 = winv[s3];
        float2 w4 = winv[s4], w5 = winv[s5], w6 = winv[s6], w7 = winv[s7];
        Q1STEP(s0, w0); Q1STEP(s1, w1); Q1STEP(s2, w2); Q1STEP(s3, w3);
        Q1STEP(s4, w4); Q1STEP(s5, w5); Q1STEP(s6, w6); Q1STEP(s7, w7);
    }
    for (; j + 4 <= end; j += 4) {
        int s0 = src[j], s1 = src[j + 1], s2 = src[j + 2], s3 = src[j + 3];
        float2 w0 = winv[s0], w1 = winv[s1], w2 = winv[s2], w3 = winv[s3];
        Q1STEP(s0, w0); Q1STEP(s1, w1); Q1STEP(s2, w2); Q1STEP(s3, w3);
    }
    for (; j < end; ++j) {
        int s = src[j]; float2 wv = winv[s];
        Q1STEP(s, wv);
    }
#undef Q1STEP
    unsigned wa = (unsigned)__builtin_amdgcn_cvt_pk_fp8_f32(ao0, ao1, 0, false);
    wa = (unsigned)__builtin_amdgcn_cvt_pk_fp8_f32(ai0, ai1, wa, true);
    unsigned wb = (unsigned)__builtin_amdgcn_cvt_pk_fp8_f32(ao2, ao3, 0, false);
    wb = (unsigned)__builtin_amdgcn_cvt_pk_fp8_f32(ai2, ai3, wb, true);
    uint2 o8; o8.x = wa; o8.y = wb;
    *(uint2*)(Q18 + (size_t)node * 128 + 8 * p) = o8;
    uint4 o;
    o.x = packbf(ao0, ao1); o.y = packbf(ai0, ai1);
    o.z = packbf(ao2, ao3); o.w = packbf(ai2, ai3);
    int tile = node >> 4, lr = node & 15, ck = p >> 2, q = p & 3;
    *(uint4*)(Q1p + (((size_t)tile * 4 + ck) * 64 + q * 16 + lr) * 8) = o;
}

__global__ void prop2_64(const unsigned char* __restrict__ Q18,
                         const unsigned short* __restrict__ HR,
                         const int* __restrict__ rowptr, const int* __restrict__ src,
                         const float2* __restrict__ winv,
                         unsigned short* __restrict__ Q2p, int n) {
    int tid = blockIdx.x * blockDim.x + threadIdx.x;
    int lane = tid & 63;
    int node = ((tid >> 6) << 2) + (lane >> 4);
    int p = lane & 15;
    if (node >= n) return;
    int beg = rowptr[node], end = rowptr[node + 1];
    float oa = 0.f, ob = 0.f, oc = 0.f, od = 0.f;
    float ia = 0.f, ib = 0.f, ic = 0.f, id = 0.f;
    int j = beg;
#define Q2STEP(s_, w_) {                                                     \
        uint2 v = *(const uint2*)(Q18 + (size_t)(s_) * 128 + 8 * p);         \
        f32x2 f0 = __builtin_amdgcn_cvt_pk_f32_fp8(v.x, false);              \
        f32x2 f1 = __builtin_amdgcn_cvt_pk_f32_fp8(v.x, true);               \
        f32x2 f2 = __builtin_amdgcn_cvt_pk_f32_fp8(v.y, false);              \
        f32x2 f3 = __builtin_amdgcn_cvt_pk_f32_fp8(v.y, true);               \
        oa = fmaf(w_.x, f0[0], oa); ob = fmaf(w_.x, f0[1], ob);              \
        ia = fmaf(w_.y, f1[0], ia); ib = fmaf(w_.y, f1[1], ib);              \
        oc = fmaf(w_.x, f2[0], oc); od = fmaf(w_.x, f2[1], od);              \
        ic = fmaf(w_.y, f3[0], ic); id = fmaf(w_.y, f3[1], id); }
    for (; j + 8 <= end; j += 8) {
        int s0 = src[j], s1 = src[j + 1], s2 = src[j + 2], s3 = src[j + 3];
        int s4 = src[j + 4], s5 = src[j + 5], s6 = src[j + 6], s7 = src[j + 7];
        float2 w0 = winv[s0], w1 = winv[s1], w2 = winv[s2], w3 = winv[s3];
        float2 w4 = winv[s4], w5 = winv[s5], w6 = winv[s6], w7 = winv[s7];
        Q2STEP(s0, w0); Q2STEP(s1, w1); Q2STEP(s2, w2); Q2STEP(s3, w3);
        Q2STEP(s4, w4); Q2STEP(s5, w5); Q2STEP(s6, w6); Q2STEP(s7, w7);
    }
    for (; j + 4 <= end; j += 4) {
        int s0 = src[j], s1 = src[j + 1], s2 = src[j + 2], s3 = src[j + 3];
        float2 w0 = winv[s0], w1 = winv[s1], w2 = winv[s2], w3 = winv[s3];
        Q2STEP(s0, w0); Q2STEP(s1, w1); Q2STEP(s2, w2); Q2STEP(s3, w3);
    }
    for (; j < end; ++j) {
        int s = src[j]; float2 wv = winv[s];
        Q2STEP(s, wv);
    }
#undef Q2STEP
    uint2 ux = *(const uint2*)(HR + (size_t)node * 64 + 4 * p);
    float xa = bflo(ux.x), xb = bfhi(ux.x), xc = bflo(ux.y), xd = bfhi(ux.y);
    uint4 o;
    o.x = packbf(2.f * oa - xa, 2.f * ob - xb);
    o.y = packbf(2.f * ia - xa, 2.f * ib - xb);
    o.z = packbf(2.f * oc - xc, 2.f * od - xd);
    o.w = packbf(2.f * ic - xc, 2.f * id - xd);
    int tile = node >> 4, lr = node & 15, ck = p >> 2, q = p & 3;
    *(uint4*)(Q2p + (((size_t)tile * 4 + ck) * 64 + q * 16 + lr) * 8) = o;
}

// ---------------- MFMA GEMMs: fragment-packed A and B, no LDS, no barriers --
// All frag loads are coalesced 1KB wave loads: lane i reads 16B at base+16i.
// mfma_f32_16x16x32_bf16 C/D: col=lane&15, row=(lane>>4)*4+reg.
// v2: small per-wave tiles for occupancy + 1-deep register prefetch on ks.

// ZR: block 32 rows x 128 cols; 4 waves each 32 rows x 32 cols (ngrp = wid).
__global__ __launch_bounds__(256) void gemm_zr_mfma(
    const unsigned short* __restrict__ XHp, const unsigned short* __restrict__ P1p,
    const unsigned short* __restrict__ P2p,
    const unsigned short* __restrict__ Wf, const float* bz,
    const float* br, const float* __restrict__ H,
    float* __restrict__ Zf, unsigned short* __restrict__ HR, int n) {
    int tid = threadIdx.x;
    int lane = tid & 63;
    int ngrp = tid >> 6;
    int rowbase = blockIdx.x * 32;
    int lr = lane & 15, quad = lane >> 4;

    int tiles[2];
#pragma unroll
    for (int mt = 0; mt < 2; ++mt) {
        int t = (rowbase >> 4) + mt;
        tiles[mt] = (t > N_TILES - 1) ? N_TILES - 1 : t;
    }

    auto LDB = [&](int ks, int nt) {
        return *(const bf8*)(Wf + (((size_t)ks * 8 + ngrp * 2 + nt) * 64 + lane) * 8);
    };
    auto LDA = [&](int ks, int mt) {
        const unsigned short* T = (ks < 4) ? XHp : (ks < 12) ? P1p : P2p;
        int ck = (ks < 4) ? ks : (ks < 12) ? ks - 4 : ks - 12;
        int nck = (ks < 4) ? 4 : 8;
        return *(const bf8*)(T + (((size_t)tiles[mt] * nck + ck) * 64 + lane) * 8);
    };

    f32x4 zero = {0.f, 0.f, 0.f, 0.f};
    f32x4 acc[2][2];
#pragma unroll
    for (int a = 0; a < 2; ++a)
#pragma unroll
        for (int b = 0; b < 2; ++b) acc[a][b] = zero;

    bf8 a0 = LDA(0, 0), a1 = LDA(0, 1), b0 = LDB(0, 0), b1 = LDB(0, 1);
#pragma unroll
    for (int ks = 0; ks < 20; ++ks) {
        bf8 na0, na1, nb0, nb1;
        if (ks < 19) {
            na0 = LDA(ks + 1, 0); na1 = LDA(ks + 1, 1);
            nb0 = LDB(ks + 1, 0); nb1 = LDB(ks + 1, 1);
        }
        acc[0][0] = __builtin_amdgcn_mfma_f32_16x16x32_bf16(a0, b0, acc[0][0], 0, 0, 0);
        acc[0][1] = __builtin_amdgcn_mfma_f32_16x16x32_bf16(a0, b1, acc[0][1], 0, 0, 0);
        acc[1][0] = __builtin_amdgcn_mfma_f32_16x16x32_bf16(a1, b0, acc[1][0], 0, 0, 0);
        acc[1][1] = __builtin_amdgcn_mfma_f32_16x16x32_bf16(a1, b1, acc[1][1], 0, 0, 0);
        if (ks < 19) { a0 = na0; a1 = na1; b0 = nb0; b1 = nb1; }
    }
#pragma unroll
    for (int mt = 0; mt < 2; ++mt)
#pragma unroll
        for (int reg = 0; reg < 4; ++reg) {
            int r = rowbase + mt * 16 + quad * 4 + reg;
            if (r >= n) continue;
#pragma unroll
            for (int nt = 0; nt < 2; ++nt) {
                int cidx = ngrp * 32 + nt * 16 + lr;
                float bias = (cidx < 64) ? bz[cidx] : br[cidx - 64];
                float v = acc[mt][nt][reg] + bias;
                float s = 1.f / (1.f + expf(-v));
                if (cidx < 64) {
                    Zf[(size_t)r * 64 + cidx] = s;
                } else {
                    int c2 = cidx - 64;
                    HR[(size_t)r * 64 + c2] = f2bfu(H[(size_t)r * 64 + c2] * s);
                }
            }
        }
}

// H~: block 32 rows x 64 cols; 4 waves = (mh = wid&1 row-tile, ngrp = wid>>1),
// each 16 rows x 32 cols. ks: 0-1 XHp, 2-5 P1p, 6-9 P2p(X-half), 10-11 HR
// (row-major strided), 12-15 Q1p, 16-19 Q2p.
__global__ __launch_bounds__(256) void gemm_h_mfma(
    const unsigned short* __restrict__ XHp, const unsigned short* __restrict__ P1p,
    const unsigned short* __restrict__ P2p, const unsigned short* __restrict__ HR,
    const unsigned short* __restrict__ Q1p, const unsigned short* __restrict__ Q2p,
    const unsigned short* __restrict__ Wf, const float* bh,
    const float* __restrict__ Zf, const float* __restrict__ H,
    float* __restrict__ out, int n) {
    int tid = threadIdx.x;
    int lane = tid & 63;
    int wid = tid >> 6;
    int mh = wid & 1, ngrp = wid >> 1;
    int rowbase = blockIdx.x * 32 + mh * 16;
    int lr = lane & 15, quad = lane >> 4;

    int t = rowbase >> 4;
    int tile = (t > N_TILES - 1) ? N_TILES - 1 : t;
    int rh = rowbase + lr;
    if (rh >= n) rh = n - 1;
    const unsigned short* hrp = HR + (size_t)rh * 64 + quad * 8;

    auto LDB = [&](int ks, int nt) {
        return *(const bf8*)(Wf + (((size_t)ks * 4 + ngrp * 2 + nt) * 64 + lane) * 8);
    };
    auto LDA = [&](int ks) {
        if (ks == 10 || ks == 11) {
            return *(const bf8*)(hrp + (ks - 10) * 32);
        }
        const unsigned short* T = (ks < 2) ? XHp : (ks < 6) ? P1p :
                                  (ks < 10) ? P2p : (ks < 16) ? Q1p : Q2p;
        int ck = (ks < 2) ? ks : (ks < 6) ? ks - 2 : (ks < 10) ? ks - 6 :
                 (ks < 16) ? ks - 12 : ks - 16;
        int nck = (ks < 2) ? 4 : (ks < 10) ? 8 : 4;
        return *(const bf8*)(T + (((size_t)tile * nck + ck) * 64 + lane) * 8);
    };

    f32x4 zero = {0.f, 0.f, 0.f, 0.f};
    f32x4 acc[2];
    acc[0] = zero; acc[1] = zero;

    bf8 a0 = LDA(0), b0 = LDB(0, 0), b1 = LDB(0, 1);
#pragma unroll
    for (int ks = 0; ks < 20; ++ks) {
        bf8 na0, nb0, nb1;
        if (ks < 19) {
            na0 = LDA(ks + 1); nb0 = LDB(ks + 1, 0); nb1 = LDB(ks + 1, 1);
        }
        acc[0] = __builtin_amdgcn_mfma_f32_16x16x32_bf16(a0, b0, acc[0], 0, 0, 0);
        acc[1] = __builtin_amdgcn_mfma_f32_16x16x32_bf16(a0, b1, acc[1], 0, 0, 0);
        if (ks < 19) { a0 = na0; b0 = nb0; b1 = nb1; }
    }
#pragma unroll
    for (int reg = 0; reg < 4; ++reg) {
        int r = rowbase + quad * 4 + reg;
        if (r >= n) continue;
#pragma unroll
        for (int nt = 0; nt < 2; ++nt) {
            int cidx = ngrp * 32 + nt * 16 + lr;
            float ht = tanhf(acc[nt][reg] + bh[cidx]);
            float z = Zf[(size_t)r * 64 + cidx];
            float h_old = H[(size_t)r * 64 + cidx];
            out[(size_t)r * 64 + cidx] = z * h_old + (1.f - z) * ht;
        }
    }
}

// ---------------- launch ----------------

static inline size_t rup(size_t x) { return (x + 63) & ~(size_t)63; }

extern "C" void kernel_launch(void* const* d_in, const int* in_sizes, int n_in,
                              void* d_out, int out_size, void* d_ws, size_t ws_size,
                              hipStream_t stream) {
    const float* X  = (const float*)d_in[0];
    const int*   EI = (const int*)d_in[1];
    const float* H  = (const float*)d_in[2];
    const float* Wz = (const float*)d_in[3];
    const float* bz = (const float*)d_in[4];
    const float* Wr = (const float*)d_in[5];
    const float* br = (const float*)d_in[6];
    const float* Wh = (const float*)d_in[7];
    const float* bh = (const float*)d_in[8];
    float* out = (float*)d_out;

    const int* row = EI;
    const int* col = EI + N_EDGES;

    char* ws = (char*)d_ws;
    size_t off = 0;
    auto carve = [&](size_t bytes) { void* p = ws + off; off += rup(bytes); return p; };

    int*   deg_out   = (int*)carve(N_NODES * 4);
    int*   deg_in    = (int*)carve(N_NODES * 4);
    int*   rowptr    = (int*)carve((N_NODES + 1) * 4);
    int*   cursor    = (int*)carve(N_NODES * 4);
    int*   blocksums = (int*)carve(64 * 4);
    float2* winv     = (float2*)carve(N_NODES * 8);
    int*   csr_src   = (int*)carve(N_EDGES * 4);
    unsigned short* XH  = (unsigned short*)carve((size_t)N_NODES * 128 * 2);  // dead after prop2_128
    unsigned char*  Pscr = (unsigned char*)carve((size_t)N_NODES * 256 + (size_t)N_TILES * 4 * 512 * 2);
    unsigned short* XHp = (unsigned short*)carve((size_t)N_TILES * 4 * 512 * 2);
    unsigned short* P1p = (unsigned short*)carve((size_t)N_TILES * 8 * 512 * 2);
    unsigned short* P2p = (unsigned short*)carve((size_t)N_TILES * 8 * 512 * 2);
    unsigned short* HR  = (unsigned short*)carve((size_t)N_NODES * 64 * 2);
    float* Zf           = (float*)carve((size_t)N_NODES * 64 * 4);
    unsigned short* Wzrf = (unsigned short*)carve(20 * 8 * 64 * 8 * 2);
    unsigned short* Whf  = (unsigned short*)carve(20 * 4 * 64 * 8 * 2);

    // P18 fp8 [n][256] lives in Pscr; dead after prop2_128, then Q1p/Q2p overlay it.
    unsigned char*  P18 = Pscr;                                // 12.8 MB fp8
    unsigned char*  Q18 = (unsigned char*)XH;                  // 6.4 MB fp8 (XH dead after prop2_128)
    unsigned short* Q1p = (unsigned short*)Pscr;               // 12.8 MB bf16 fragments
    unsigned short* Q2p = (unsigned short*)(Pscr + (size_t)N_NODES * 256);  // 12.8 MB

    hipMemsetAsync(deg_out, 0, rup(N_NODES * 4) + rup(N_NODES * 4), stream);
    count_deg<<<(N_EDGES + 255) / 256, 256, 0, stream>>>(row, col, deg_out, deg_in, N_EDGES);

    int nblk = (N_NODES + 1023) / 1024;
    scan_block<<<nblk, 1024, 0, stream>>>(deg_in, rowptr, blocksums, N_NODES);
    scan_sums<<<1, 64, 0, stream>>>(blocksums, nblk);
    scan_add<<<(N_NODES + 1 + 255) / 256, 256, 0, stream>>>(rowptr, blocksums, cursor,
                                                            deg_out, deg_in, winv, N_NODES, N_EDGES);

    // fused: build_csr + concat_xh + pack_weights
    fused_prep<<<CSR_BLOCKS + CONCAT_BLOCKS + PACK_BLOCKS, 256, 0, stream>>>(
        row, col, cursor, csr_src,
        X, H, XH, XHp, Wz, Wr, Wh, Wzrf, Whf, N_NODES, N_EDGES);

    // props on XH: 2 nodes/wave
    int blocks_p128 = (((N_NODES + 1) / 2) * 64 + 255) / 256;
    prop1_128<<<blocks_p128, 256, 0, stream>>>(XH, rowptr, csr_src, winv, P18, P1p, N_NODES);
    prop2_128<<<blocks_p128, 256, 0, stream>>>(P18, XH, rowptr, csr_src, winv, P2p, N_NODES);

    // Z|R GEMM -> Zf, HR   (XH, P18 now dead)
    int zr_blocks = (N_NODES + 31) / 32;
    gemm_zr_mfma<<<zr_blocks, 256, 0, stream>>>(XHp, P1p, P2p, Wzrf, bz, br, H, Zf, HR, N_NODES);

    // props on HR: 4 nodes/wave
    int blocks_p64 = (((N_NODES + 3) / 4) * 64 + 255) / 256;
    prop1_64<<<blocks_p64, 256, 0, stream>>>(HR, rowptr, csr_src, winv, Q18, Q1p, N_NODES);
    prop2_64<<<blocks_p64, 256, 0, stream>>>(Q18, HR, rowptr, csr_src, winv, Q2p, N_NODES);

    // H~ GEMM + GRU mix -> out
    int h_blocks = (N_NODES + 31) / 32;
    gemm_h_mfma<<<h_blocks, 256, 0, stream>>>(XHp, P1p, P2p, HR, Q1p, Q2p,
                                              Whf, bh, Zf, H, out, N_NODES);
}